// Round 1
// baseline (1466.686 us; speedup 1.0000x reference)
//
#include <hip/hip_runtime.h>
#include <hip/hip_bf16.h>
#include <math.h>

#define N_NODES 100000
#define N_EDGES 1600000
#define D_IN    384
#define D_HID   768
#define D_OUT   256

typedef unsigned short ushort_t;
typedef __attribute__((ext_vector_type(8))) short bf16x8;
typedef __attribute__((ext_vector_type(4))) float f32x4;

#define MFMA(a, b, c) __builtin_amdgcn_mfma_f32_16x16x32_bf16((a), (b), (c), 0, 0, 0)

__device__ __forceinline__ ushort_t f2bf(float f) {
    unsigned u = __builtin_bit_cast(unsigned, f);
    u += 0x7fffu + ((u >> 16) & 1u);   // RNE
    return (ushort_t)(u >> 16);
}
__device__ __forceinline__ float bf2f(ushort_t h) {
    return __builtin_bit_cast(float, ((unsigned)h) << 16);
}
__device__ __forceinline__ float gelu_f(float x) {
    // tanh-form GELU as x * sigmoid(2u), 2u = 1.5957691 x + 0.0713549 x^3
    float x2 = x * x;
    float tt = x * fmaf(x2, -0.0713549f, -1.5957691f);
    float e = __expf(tt);                       // exp(-2u)
    return x * __builtin_amdgcn_rcpf(1.f + e);  // x * sigmoid(2u)
}

// 8 consecutive fp32 -> bf16x8 MFMA fragment, 2 loads + 4 cvt_pk (RNE)
__device__ __forceinline__ bf16x8 load_cvt8(const float* __restrict__ p) {
    float4 va = *(const float4*)p;
    float4 vb = *(const float4*)(p + 4);
    union { unsigned u[4]; bf16x8 v; } r;
    asm("v_cvt_pk_bf16_f32 %0, %1, %2" : "=v"(r.u[0]) : "v"(va.x), "v"(va.y));
    asm("v_cvt_pk_bf16_f32 %0, %1, %2" : "=v"(r.u[1]) : "v"(va.z), "v"(va.w));
    asm("v_cvt_pk_bf16_f32 %0, %1, %2" : "=v"(r.u[2]) : "v"(vb.x), "v"(vb.y));
    asm("v_cvt_pk_bf16_f32 %0, %1, %2" : "=v"(r.u[3]) : "v"(vb.z), "v"(vb.w));
    return r.v;
}

// ---------------------------------------------------------------------------
// transpose + fp32->bf16: WT[n*K + k] = bf16(W[k*N + n])
// ---------------------------------------------------------------------------
__global__ __launch_bounds__(256) void transconv_kernel(
    const float* __restrict__ W, ushort_t* __restrict__ WT, int K, int N)
{
    int idx = blockIdx.x * 256 + threadIdx.x;
    if (idx >= K * N) return;
    int n = idx / K, k = idx % K;
    WT[idx] = f2bf(W[(size_t)k * N + n]);
}

// ---------------------------------------------------------------------------
// CSR build
// ---------------------------------------------------------------------------
__global__ __launch_bounds__(256) void hist_kernel(
    const int* __restrict__ edges, int* __restrict__ deg)
{
    int e = blockIdx.x * 256 + threadIdx.x;
    atomicAdd(&deg[edges[N_EDGES + e]], 1);
}

__global__ __launch_bounds__(1024) void scan_kernel(
    const int* __restrict__ deg, int* __restrict__ rowptr,
    int* __restrict__ cursor)
{
    __shared__ int sums[1024];
    const int t = threadIdx.x;
    const int CH = (N_NODES + 1023) / 1024;
    int start = t * CH;
    int end = start + CH; if (end > N_NODES) end = N_NODES;
    int s = 0;
    for (int j = start; j < end; ++j) s += deg[j];
    sums[t] = s;
    __syncthreads();
    for (int off = 1; off < 1024; off <<= 1) {
        int v = (t >= off) ? sums[t - off] : 0;
        __syncthreads();
        sums[t] += v;
        __syncthreads();
    }
    int run = sums[t] - s;
    for (int j = start; j < end; ++j) {
        rowptr[j] = run;
        cursor[j] = run;
        run += deg[j];
    }
    if (start < N_NODES && end == N_NODES) rowptr[N_NODES] = run;
}

__global__ __launch_bounds__(256) void fill_kernel(
    const int* __restrict__ edges, int* __restrict__ cursor,
    int* __restrict__ eid)
{
    int e = blockIdx.x * 256 + threadIdx.x;
    int d = edges[N_EDGES + e];
    int pos = atomicAdd(&cursor[d], 1);
    eid[pos] = edges[e];
}

// ---------------------------------------------------------------------------
// K1: MFMA encoder. 32 rows/block, 8 waves (512 threads).
//   GEMM1: [32x384]@[384x768]; wave owns 96-col slice, acc[2][6].
//     A-fragments read straight from global X (fp32) + in-reg cvt_pk -> no Xs
//     LDS tile, no staging barrier. Block X tile (48KB fp32) is L1/L2-hot.
//   LN(768)+GELU -> bf16 H1 in LDS
//   GEMM2: [32x768]@[768x256]; wave owns 32-col slice, acc[2][2]
//   H written bf16 via LDS bounce (reuse H1s) for coalesced 32B stores.
// LDS ~52KB (was 76.5KB); __launch_bounds__(512,4) caps VGPR at 128 so two
// 8-wave blocks co-reside: 16 waves/CU (was 8).
// MFMA 16x16x32 layouts (verified m89/m91/m120):
//   A[m=lane&15][k=(lane>>4)*8+j]  (8 contig bf16 from row m)
//   B from W^T row n=lane&15, same k pattern
//   C/D: col(N)=lane&15, row(M)=(lane>>4)*4+reg
// ---------------------------------------------------------------------------
#define BM 32
#define S2 776   // H1s stride (768+8) bf16 -> 1552B, 16B-aligned
#define SO 264   // out-bounce stride (256+8) bf16 -> 528B, 16B-aligned

__global__ __launch_bounds__(512, 4) void encoder_mfma(
    const float* __restrict__ X, const ushort_t* __restrict__ W1T,
    const float* __restrict__ b1, const float* __restrict__ g1,
    const float* __restrict__ be1, const ushort_t* __restrict__ W2T,
    const float* __restrict__ b2, ushort_t* __restrict__ Hbf)
{
    __shared__ __align__(16) ushort_t H1s[BM * S2];     // 49664 B
    __shared__ float redS[BM * 8], redS2[BM * 8];       // 2048 B
    __shared__ float muS[BM], rsS[BM];                  // 256 B

    const int t = threadIdx.x;
    const int w = t >> 6, lane = t & 63;
    const int q = lane >> 4, mcol = lane & 15;
    const int kq = q * 8;
    const int row0 = blockIdx.x * BM;

    // ---- GEMM1 ----
    f32x4 acc1[2][6];
    #pragma unroll
    for (int mt = 0; mt < 2; ++mt)
        #pragma unroll
        for (int nt = 0; nt < 6; ++nt)
            acc1[mt][nt] = (f32x4){0.f, 0.f, 0.f, 0.f};

    const float* Xr0 = X + (size_t)(row0 + mcol) * D_IN + kq;
    const float* Xr1 = Xr0 + (size_t)16 * D_IN;
    const ushort_t* Wb1 = W1T + (size_t)(w * 96 + mcol) * D_IN + kq;

    for (int kk = 0; kk < D_IN; kk += 32) {
        bf16x8 a0 = load_cvt8(Xr0 + kk);
        bf16x8 a1 = load_cvt8(Xr1 + kk);
        #pragma unroll
        for (int nt = 0; nt < 6; ++nt) {
            bf16x8 b = *(const bf16x8*)&Wb1[(size_t)(nt * 16) * D_IN + kk];
            acc1[0][nt] = MFMA(a0, b, acc1[0][nt]);
            acc1[1][nt] = MFMA(a1, b, acc1[1][nt]);
        }
    }

    // bias b1 (per col, must precede LN stats)
    #pragma unroll
    for (int nt = 0; nt < 6; ++nt) {
        float bv = b1[w * 96 + nt * 16 + mcol];
        #pragma unroll
        for (int mt = 0; mt < 2; ++mt)
            #pragma unroll
            for (int reg = 0; reg < 4; ++reg)
                acc1[mt][nt][reg] += bv;
    }

    // LN stats: per-row sums over this wave's 96 cols, then cross-wave via LDS
    #pragma unroll
    for (int mt = 0; mt < 2; ++mt) {
        #pragma unroll
        for (int reg = 0; reg < 4; ++reg) {
            float s = 0.f, s2 = 0.f;
            #pragma unroll
            for (int nt = 0; nt < 6; ++nt) {
                float v = acc1[mt][nt][reg];
                s += v; s2 += v * v;
            }
            #pragma unroll
            for (int m = 1; m <= 8; m <<= 1) {
                s  += __shfl_xor(s,  m, 64);
                s2 += __shfl_xor(s2, m, 64);
            }
            if (mcol == 0) {
                int row = mt * 16 + q * 4 + reg;
                redS[row * 8 + w] = s;
                redS2[row * 8 + w] = s2;
            }
        }
    }
    __syncthreads();
    if (t < BM) {
        float s = 0.f, s2 = 0.f;
        #pragma unroll
        for (int j = 0; j < 8; ++j) { s += redS[t * 8 + j]; s2 += redS2[t * 8 + j]; }
        float mu = s / 768.f;
        float var = s2 / 768.f - mu * mu;
        muS[t] = mu;
        rsS[t] = rsqrtf(var + 1e-5f);
    }
    __syncthreads();

    // LN + GELU -> bf16 H1s
    {
        float muR[2][4], rsR[2][4];
        #pragma unroll
        for (int mt = 0; mt < 2; ++mt)
            #pragma unroll
            for (int reg = 0; reg < 4; ++reg) {
                int row = mt * 16 + q * 4 + reg;
                muR[mt][reg] = muS[row];
                rsR[mt][reg] = rsS[row];
            }
        #pragma unroll
        for (int nt = 0; nt < 6; ++nt) {
            int c = w * 96 + nt * 16 + mcol;
            float gv = g1[c], bev = be1[c];
            #pragma unroll
            for (int mt = 0; mt < 2; ++mt)
                #pragma unroll
                for (int reg = 0; reg < 4; ++reg) {
                    int row = mt * 16 + q * 4 + reg;
                    float v = fmaf((acc1[mt][nt][reg] - muR[mt][reg]) * rsR[mt][reg], gv, bev);
                    H1s[row * S2 + c] = f2bf(gelu_f(v));
                }
        }
    }
    __syncthreads();

    // ---- GEMM2 ----
    f32x4 acc2[2][2];
    #pragma unroll
    for (int mt = 0; mt < 2; ++mt)
        #pragma unroll
        for (int nt = 0; nt < 2; ++nt)
            acc2[mt][nt] = (f32x4){0.f, 0.f, 0.f, 0.f};

    const ushort_t* Wb2 = W2T + (size_t)(w * 32 + mcol) * D_HID + kq;
    for (int kk = 0; kk < D_HID; kk += 32) {
        bf16x8 a0 = *(const bf16x8*)&H1s[(0 * 16 + mcol) * S2 + kk + kq];
        bf16x8 a1 = *(const bf16x8*)&H1s[(1 * 16 + mcol) * S2 + kk + kq];
        #pragma unroll
        for (int nt = 0; nt < 2; ++nt) {
            bf16x8 b = *(const bf16x8*)&Wb2[(size_t)(nt * 16) * D_HID + kk];
            acc2[0][nt] = MFMA(a0, b, acc2[0][nt]);
            acc2[1][nt] = MFMA(a1, b, acc2[1][nt]);
        }
    }
    __syncthreads();   // all waves done reading H1s; safe to reuse as bounce

    // epilogue: +b2, bf16, bounce via LDS (reuse H1s) for coalesced stores
    ushort_t* Ox = H1s;  // 32*264 <= 32*776
    {
        #pragma unroll
        for (int nt = 0; nt < 2; ++nt) {
            int col = w * 32 + nt * 16 + mcol;
            float bv = b2[col];
            #pragma unroll
            for (int mt = 0; mt < 2; ++mt)
                #pragma unroll
                for (int reg = 0; reg < 4; ++reg) {
                    int row = mt * 16 + q * 4 + reg;
                    Ox[row * SO + col] = f2bf(acc2[mt][nt][reg] + bv);
                }
        }
    }
    __syncthreads();
    {
        // 32 rows x 16 segs; each seg = 16 bf16 = 32B = TWO uint4
        int r = t >> 4, seg = t & 15;
        const uint4* src = (const uint4*)&Ox[r * SO + seg * 16];
        uint4* dst = (uint4*)&Hbf[(size_t)(row0 + r) * D_OUT + seg * 16];
        dst[0] = src[0];
        dst[1] = src[1];
    }
}

// ---------------------------------------------------------------------------
// K2: fused aggregation + dual-MFMA + residual + LN. 16 rows/block, 4 waves.
// ---------------------------------------------------------------------------
#define SA 264   // (256+8) bf16

__global__ __launch_bounds__(256) void aggfin_mfma(
    const ushort_t* __restrict__ Hbf, const int* __restrict__ rowptr,
    const int* __restrict__ eid,
    const ushort_t* __restrict__ WlT, const float* __restrict__ bl,
    const ushort_t* __restrict__ WrT, const float* __restrict__ g2,
    const float* __restrict__ be2, float* __restrict__ out)
{
    __shared__ __align__(16) ushort_t Ma[16 * SA];
    __shared__ __align__(16) ushort_t Ha[16 * SA];
    __shared__ float redS[16 * 4], redS2[16 * 4], muS[16], rsS[16];

    const int t = threadIdx.x;
    const int w = t >> 6, lane = t & 63;
    const int q = lane >> 4, mcol = lane & 15;
    const int kq = q * 8;
    const int row0 = blockIdx.x * 16;

    // gather: mean over neighbors, per dim t
    #pragma unroll 1
    for (int r = 0; r < 16; ++r) {
        int n = row0 + r;
        int start = rowptr[n], end = rowptr[n + 1];
        float acc = 0.f;
        int e = start;
        for (; e + 4 <= end; e += 4) {
            int s0 = eid[e], s1 = eid[e + 1], s2 = eid[e + 2], s3 = eid[e + 3];
            acc += bf2f(Hbf[(size_t)s0 * D_OUT + t]) + bf2f(Hbf[(size_t)s1 * D_OUT + t])
                 + bf2f(Hbf[(size_t)s2 * D_OUT + t]) + bf2f(Hbf[(size_t)s3 * D_OUT + t]);
        }
        for (; e < end; ++e) acc += bf2f(Hbf[(size_t)eid[e] * D_OUT + t]);
        float inv = (end > start) ? 1.f / (float)(end - start) : 1.f;
        Ma[r * SA + t] = f2bf(acc * inv);
        Ha[r * SA + t] = Hbf[(size_t)n * D_OUT + t];
    }
    __syncthreads();

    // dual MFMA: sage = mean@Wl + h@Wr  (M=16, N=256, K=256)
    f32x4 acc[4];
    #pragma unroll
    for (int nt = 0; nt < 4; ++nt) acc[nt] = (f32x4){0.f, 0.f, 0.f, 0.f};

    for (int kk = 0; kk < D_OUT; kk += 32) {
        bf16x8 am = *(const bf16x8*)&Ma[mcol * SA + kk + kq];
        bf16x8 ah = *(const bf16x8*)&Ha[mcol * SA + kk + kq];
        #pragma unroll
        for (int nt = 0; nt < 4; ++nt) {
            int n = w * 64 + nt * 16 + mcol;
            bf16x8 bL = *(const bf16x8*)&WlT[(size_t)n * D_OUT + kk + kq];
            bf16x8 bR = *(const bf16x8*)&WrT[(size_t)n * D_OUT + kk + kq];
            acc[nt] = MFMA(am, bL, acc[nt]);
            acc[nt] = MFMA(ah, bR, acc[nt]);
        }
    }

    // y = h + sage + bl ; LN over 256 cols
    float y[4][4];
    {
        #pragma unroll
        for (int nt = 0; nt < 4; ++nt) {
            int col = w * 64 + nt * 16 + mcol;
            float bv = bl[col];
            #pragma unroll
            for (int reg = 0; reg < 4; ++reg) {
                int row = q * 4 + reg;
                y[nt][reg] = acc[nt][reg] + bv + bf2f(Ha[row * SA + col]);
            }
        }
    }
    #pragma unroll
    for (int reg = 0; reg < 4; ++reg) {
        float s = 0.f, s2 = 0.f;
        #pragma unroll
        for (int nt = 0; nt < 4; ++nt) { float v = y[nt][reg]; s += v; s2 += v * v; }
        #pragma unroll
        for (int m = 1; m <= 8; m <<= 1) {
            s  += __shfl_xor(s,  m, 64);
            s2 += __shfl_xor(s2, m, 64);
        }
        if (mcol == 0) {
            int row = q * 4 + reg;
            redS[row * 4 + w] = s;
            redS2[row * 4 + w] = s2;
        }
    }
    __syncthreads();
    if (t < 16) {
        float s  = redS[t * 4] + redS[t * 4 + 1] + redS[t * 4 + 2] + redS[t * 4 + 3];
        float s2 = redS2[t * 4] + redS2[t * 4 + 1] + redS2[t * 4 + 2] + redS2[t * 4 + 3];
        float mu = s / 256.f;
        float var = s2 / 256.f - mu * mu;
        muS[t] = mu;
        rsS[t] = rsqrtf(var + 1e-5f);
    }
    __syncthreads();
    {
        #pragma unroll
        for (int nt = 0; nt < 4; ++nt) {
            int col = w * 64 + nt * 16 + mcol;
            float gv = g2[col], bv = be2[col];
            #pragma unroll
            for (int reg = 0; reg < 4; ++reg) {
                int row = q * 4 + reg;
                out[(size_t)(row0 + row) * D_OUT + col] =
                    (y[nt][reg] - muS[row]) * rsS[row] * gv + bv;
            }
        }
    }
}

extern "C" void kernel_launch(void* const* d_in, const int* in_sizes, int n_in,
                              void* d_out, int out_size, void* d_ws, size_t ws_size,
                              hipStream_t stream)
{
    const float* X   = (const float*)d_in[0];
    const int*   edg = (const int*)  d_in[1];
    const float* W1  = (const float*)d_in[2];
    const float* b1  = (const float*)d_in[3];
    const float* g1  = (const float*)d_in[4];
    const float* be1 = (const float*)d_in[5];
    const float* W2  = (const float*)d_in[6];
    const float* b2  = (const float*)d_in[7];
    const float* Wl  = (const float*)d_in[8];
    const float* bl  = (const float*)d_in[9];
    const float* Wr  = (const float*)d_in[10];
    const float* g2  = (const float*)d_in[11];
    const float* be2 = (const float*)d_in[12];

    float* out = (float*)d_out;

    // workspace layout (all 16B aligned)
    char* p = (char*)d_ws;
    ushort_t* Hbf = (ushort_t*)p;  p += (size_t)N_NODES * D_OUT * sizeof(ushort_t); // 51.2MB
    ushort_t* W1T = (ushort_t*)p;  p += (size_t)D_HID * D_IN * sizeof(ushort_t);
    ushort_t* W2T = (ushort_t*)p;  p += (size_t)D_OUT * D_HID * sizeof(ushort_t);
    ushort_t* WlT = (ushort_t*)p;  p += (size_t)D_OUT * D_OUT * sizeof(ushort_t);
    ushort_t* WrT = (ushort_t*)p;  p += (size_t)D_OUT * D_OUT * sizeof(ushort_t);
    int* deg    = (int*)p;         p += (size_t)(N_NODES + 16) * sizeof(int);
    int* rowptr = (int*)p;         p += (size_t)(N_NODES + 16) * sizeof(int);
    int* cursor = (int*)p;         p += (size_t)(N_NODES + 16) * sizeof(int);
    int* eid    = (int*)p;

    hipMemsetAsync(deg, 0, (size_t)N_NODES * sizeof(int), stream);

    // weight prep (bf16 transposes)
    transconv_kernel<<<(D_IN * D_HID + 255) / 256, 256, 0, stream>>>(W1, W1T, D_IN, D_HID);
    transconv_kernel<<<(D_HID * D_OUT + 255) / 256, 256, 0, stream>>>(W2, W2T, D_HID, D_OUT);
    transconv_kernel<<<(D_OUT * D_OUT + 255) / 256, 256, 0, stream>>>(Wl, WlT, D_OUT, D_OUT);
    transconv_kernel<<<(D_OUT * D_OUT + 255) / 256, 256, 0, stream>>>(Wr, WrT, D_OUT, D_OUT);

    // CSR build
    hist_kernel<<<N_EDGES / 256, 256, 0, stream>>>(edg, deg);
    scan_kernel<<<1, 1024, 0, stream>>>(deg, rowptr, cursor);
    fill_kernel<<<N_EDGES / 256, 256, 0, stream>>>(edg, cursor, eid);

    // main pipeline
    encoder_mfma<<<N_NODES / BM, 512, 0, stream>>>(X, W1T, b1, g1, be1, W2T, b2, Hbf);
    aggfin_mfma<<<N_NODES / 16, 256, 0, stream>>>(Hbf, rowptr, eid, WlT, bl, WrT, g2, be2, out);
}

// Round 2
// 1030.995 us; speedup vs baseline: 1.4226x; 1.4226x over previous
//
#include <hip/hip_runtime.h>
#include <hip/hip_bf16.h>
#include <math.h>

#define N_NODES 100000
#define N_EDGES 1600000
#define D_IN    384
#define D_HID   768
#define D_OUT   256

typedef unsigned short ushort_t;
typedef __attribute__((ext_vector_type(8))) short bf16x8;
typedef __attribute__((ext_vector_type(4))) float f32x4;

#define MFMA(a, b, c) __builtin_amdgcn_mfma_f32_16x16x32_bf16((a), (b), (c), 0, 0, 0)

__device__ __forceinline__ ushort_t f2bf(float f) {
    unsigned u = __builtin_bit_cast(unsigned, f);
    u += 0x7fffu + ((u >> 16) & 1u);   // RNE
    return (ushort_t)(u >> 16);
}
__device__ __forceinline__ float bf2f(ushort_t h) {
    return __builtin_bit_cast(float, ((unsigned)h) << 16);
}
__device__ __forceinline__ float gelu_f(float x) {
    // tanh-form GELU as x * sigmoid(2u), 2u = 1.5957691 x + 0.0713549 x^3
    float x2 = x * x;
    float tt = x * fmaf(x2, -0.0713549f, -1.5957691f);
    float e = __expf(tt);                       // exp(-2u)
    return x * __builtin_amdgcn_rcpf(1.f + e);  // x * sigmoid(2u)
}

// 8 consecutive fp32 -> bf16x8 MFMA fragment, 2 loads + 4 cvt_pk (RNE)
__device__ __forceinline__ bf16x8 load_cvt8(const float* __restrict__ p) {
    float4 va = *(const float4*)p;
    float4 vb = *(const float4*)(p + 4);
    union { unsigned u[4]; bf16x8 v; } r;
    asm("v_cvt_pk_bf16_f32 %0, %1, %2" : "=v"(r.u[0]) : "v"(va.x), "v"(va.y));
    asm("v_cvt_pk_bf16_f32 %0, %1, %2" : "=v"(r.u[1]) : "v"(va.z), "v"(va.w));
    asm("v_cvt_pk_bf16_f32 %0, %1, %2" : "=v"(r.u[2]) : "v"(vb.x), "v"(vb.y));
    asm("v_cvt_pk_bf16_f32 %0, %1, %2" : "=v"(r.u[3]) : "v"(vb.z), "v"(vb.w));
    return r.v;
}

// global -> LDS direct, 16B per lane (wave-uniform LDS base + lane*16)
typedef __attribute__((address_space(1))) const unsigned GASU;
typedef __attribute__((address_space(3))) unsigned LASU;
__device__ __forceinline__ void gll16(const void* g, void* l) {
    __builtin_amdgcn_global_load_lds((GASU*)g, (LASU*)l, 16, 0, 0);
}

// ---------------------------------------------------------------------------
// transpose + fp32->bf16: WT[n*K + k] = bf16(W[k*N + n])
// ---------------------------------------------------------------------------
__global__ __launch_bounds__(256) void transconv_kernel(
    const float* __restrict__ W, ushort_t* __restrict__ WT, int K, int N)
{
    int idx = blockIdx.x * 256 + threadIdx.x;
    if (idx >= K * N) return;
    int n = idx / K, k = idx % K;
    WT[idx] = f2bf(W[(size_t)k * N + n]);
}

// ---------------------------------------------------------------------------
// CSR build
// ---------------------------------------------------------------------------
__global__ __launch_bounds__(256) void hist_kernel(
    const int* __restrict__ edges, int* __restrict__ deg)
{
    int e = blockIdx.x * 256 + threadIdx.x;
    atomicAdd(&deg[edges[N_EDGES + e]], 1);
}

#define NBS 98   // ceil(100000/1024)

__global__ __launch_bounds__(1024) void scan1_kernel(
    const int* __restrict__ deg, int* __restrict__ bsum)
{
    __shared__ int wsum[16];
    int t = threadIdx.x;
    int i = blockIdx.x * 1024 + t;
    int v = (i < N_NODES) ? deg[i] : 0;
    #pragma unroll
    for (int m = 1; m <= 32; m <<= 1) v += __shfl_xor(v, m, 64);
    if ((t & 63) == 0) wsum[t >> 6] = v;
    __syncthreads();
    if (t < 16) {
        int s = wsum[t];
        #pragma unroll
        for (int m = 1; m <= 8; m <<= 1) s += __shfl_xor(s, m, 16);
        if (t == 0) bsum[blockIdx.x] = s;
    }
}

__global__ __launch_bounds__(64) void scan2_kernel(
    const int* __restrict__ bsum, int* __restrict__ boff, int* __restrict__ rowptr)
{
    if (threadIdx.x == 0) {
        int r = 0;
        for (int i = 0; i < NBS; ++i) { boff[i] = r; r += bsum[i]; }
        rowptr[N_NODES] = r;
    }
}

__global__ __launch_bounds__(1024) void scan3_kernel(
    const int* __restrict__ deg, const int* __restrict__ boff,
    int* __restrict__ rowptr, int* __restrict__ cursor)
{
    __shared__ int sc[1024];
    int t = threadIdx.x;
    int i = blockIdx.x * 1024 + t;
    int v = (i < N_NODES) ? deg[i] : 0;
    sc[t] = v;
    __syncthreads();
    for (int off = 1; off < 1024; off <<= 1) {
        int u = (t >= off) ? sc[t - off] : 0;
        __syncthreads();
        sc[t] += u;
        __syncthreads();
    }
    int excl = sc[t] - v;
    if (i < N_NODES) {
        int rp = boff[blockIdx.x] + excl;
        rowptr[i] = rp;
        cursor[i] = rp;
    }
}

__global__ __launch_bounds__(256) void fill_kernel(
    const int* __restrict__ edges, int* __restrict__ cursor,
    int* __restrict__ eid)
{
    int e = blockIdx.x * 256 + threadIdx.x;
    int d = edges[N_EDGES + e];
    int pos = atomicAdd(&cursor[d], 1);
    eid[pos] = edges[e];
}

// ---------------------------------------------------------------------------
// K1: LDS-tiled double-buffered MFMA encoder. BM=64 rows/block, 8 waves.
// All MFMA operands come from LDS; weights streamed via global_load_lds(16B)
// with XOR slot-swizzle (slot = q ^ ((n>>1)&3)) applied on the GLOBAL source
// address (linear LDS dest) and on the ds_read offset -> 2-way-free b128.
//
// LDS layout (151040 B total, 1 block/CU by design):
//   [0      ) XT   64 x 392 bf16 (50176)     | aliased later by H1 (64x776)
//   [50176  ) W1B0 768 x 32 bf16 (49152)     |   H1 = XT+W1B0 = 99328 exact
//   [99328  ) W1B1 (49152) | W2B0(16K)+W2B1(16K) | Obuf 64x264 bf16 (33792)
//   [148480 ) redS/redS2/muS/rsS (2560)
//
// Wave grid 2M x 4N. GEMM1: wave = 32 rows x 192 cols, acc[2][12].
// GEMM2: wave = 32 rows x 64 cols, acc[2][4].
// MFMA 16x16x32 layouts (verified m89/m91/m120):
//   A[m=lane&15][k=(lane>>4)*8+j], B row n=lane&15 same k pattern,
//   C/D col=lane&15, row=(lane>>4)*4+reg
// ---------------------------------------------------------------------------
#define BM 64
#define SX 392    // XT stride (bf16)
#define SH 776    // H1 stride (bf16)
#define SO 264    // out-bounce stride (bf16)

#define OFF_XT   0
#define OFF_W1B0 50176
#define OFF_W1B1 99328
#define OFF_W2B0 99328
#define OFF_W2B1 115712
#define OFF_OB   99328
#define OFF_H1   0
#define OFF_RED  148480
#define OFF_RED2 149504
#define OFF_MU   150528
#define OFF_RS   150784
#define LDS_TOT  151040

// stage a [768 n x 32 k] bf16 W1 K-slice: 6 x 1KB gll per wave
__device__ __forceinline__ void stage_w1(
    const ushort_t* __restrict__ W1T, char* buf, int w, int lane, int kk)
{
    int qsrc = (lane & 3) ^ ((lane >> 3) & 3);   // slot->k-quarter (involution)
    #pragma unroll
    for (int j = 0; j < 6; ++j) {
        int n = (w * 6 + j) * 16 + (lane >> 2);
        gll16(W1T + (size_t)n * D_IN + kk + qsrc * 8, buf + (w * 6 + j) * 1024);
    }
}

// stage a [256 n x 32 k] bf16 W2 K-slice: 2 x 1KB gll per wave
__device__ __forceinline__ void stage_w2(
    const ushort_t* __restrict__ W2T, char* buf, int w, int lane, int kk)
{
    int qsrc = (lane & 3) ^ ((lane >> 3) & 3);
    #pragma unroll
    for (int j = 0; j < 2; ++j) {
        int n = (w * 2 + j) * 16 + (lane >> 2);
        gll16(W2T + (size_t)n * D_HID + kk + qsrc * 8, buf + (w * 2 + j) * 1024);
    }
}

__global__ __launch_bounds__(512, 2) void encoder_mfma(
    const float* __restrict__ X, const ushort_t* __restrict__ W1T,
    const float* __restrict__ b1, const float* __restrict__ g1,
    const float* __restrict__ be1, const ushort_t* __restrict__ W2T,
    const float* __restrict__ b2, ushort_t* __restrict__ Hbf)
{
    __shared__ __align__(16) char LB[LDS_TOT];

    const int t = threadIdx.x;
    const int w = t >> 6, lane = t & 63;
    const int wm = w >> 2, wn = w & 3;
    const int q = lane >> 4, mcol = lane & 15;
    const int kq = q * 8;
    const int sw = ((q ^ ((mcol >> 1) & 3)) << 4);  // swizzled 16B slot offset
    const int row0 = blockIdx.x * BM;

    ushort_t* XTu = (ushort_t*)(LB + OFF_XT);
    float* redS  = (float*)(LB + OFF_RED);
    float* redS2 = (float*)(LB + OFF_RED2);
    float* muS   = (float*)(LB + OFF_MU);
    float* rsS   = (float*)(LB + OFF_RS);

    // ---- prologue: issue W1 step-0 stage, then stage X tile (fp32->bf16) ----
    stage_w1(W1T, LB + OFF_W1B0, w, lane, 0);
    #pragma unroll
    for (int j = 0; j < 6; ++j) {
        int seg = t + j * 512;             // 3072 segs of 8 floats
        int row = seg / 48, cs = seg % 48;
        int rg = row0 + row; if (rg > N_NODES - 1) rg = N_NODES - 1;
        bf16x8 v = load_cvt8(X + (size_t)rg * D_IN + cs * 8);
        *(bf16x8*)&XTu[row * SX + cs * 8] = v;
    }
    __syncthreads();

    // ---- GEMM1: [64x384] @ [384x768], 12 K-steps, double-buffered ----
    f32x4 acc1[2][12];
    #pragma unroll
    for (int mt = 0; mt < 2; ++mt)
        #pragma unroll
        for (int nt = 0; nt < 12; ++nt)
            acc1[mt][nt] = (f32x4){0.f, 0.f, 0.f, 0.f};

    #pragma unroll 1
    for (int s = 0; s < 12; ++s) {
        if (s < 11)
            stage_w1(W1T, LB + ((s & 1) ? OFF_W1B0 : OFF_W1B1), w, lane, (s + 1) * 32);
        const int kk = s * 32;
        const char* wb = LB + ((s & 1) ? OFF_W1B1 : OFF_W1B0);
        bf16x8 a0 = *(const bf16x8*)&XTu[(wm * 32 + mcol) * SX + kk + kq];
        bf16x8 a1 = *(const bf16x8*)&XTu[(wm * 32 + 16 + mcol) * SX + kk + kq];
        #pragma unroll
        for (int nt = 0; nt < 12; ++nt) {
            int nl = wn * 192 + nt * 16 + mcol;
            bf16x8 b = *(const bf16x8*)(wb + nl * 64 + sw);
            acc1[0][nt] = MFMA(a0, b, acc1[0][nt]);
            acc1[1][nt] = MFMA(a1, b, acc1[1][nt]);
        }
        __syncthreads();
    }

    // prefetch W2 step-0 (into W1B1 region - dead now) under the LN phase
    stage_w2(W2T, LB + OFF_W2B0, w, lane, 0);

    // ---- bias b1 + LN stats ----
    #pragma unroll
    for (int nt = 0; nt < 12; ++nt) {
        float bv = b1[wn * 192 + nt * 16 + mcol];
        #pragma unroll
        for (int mt = 0; mt < 2; ++mt)
            #pragma unroll
            for (int reg = 0; reg < 4; ++reg)
                acc1[mt][nt][reg] += bv;
    }
    #pragma unroll
    for (int mt = 0; mt < 2; ++mt) {
        #pragma unroll
        for (int reg = 0; reg < 4; ++reg) {
            float s = 0.f, s2 = 0.f;
            #pragma unroll
            for (int nt = 0; nt < 12; ++nt) {
                float v = acc1[mt][nt][reg];
                s += v; s2 += v * v;
            }
            #pragma unroll
            for (int m = 1; m <= 8; m <<= 1) {
                s  += __shfl_xor(s,  m, 64);
                s2 += __shfl_xor(s2, m, 64);
            }
            if (mcol == 0) {
                int row = wm * 32 + mt * 16 + q * 4 + reg;
                redS[row * 4 + wn] = s;
                redS2[row * 4 + wn] = s2;
            }
        }
    }
    __syncthreads();
    if (t < BM) {
        float s  = redS[t * 4] + redS[t * 4 + 1] + redS[t * 4 + 2] + redS[t * 4 + 3];
        float s2 = redS2[t * 4] + redS2[t * 4 + 1] + redS2[t * 4 + 2] + redS2[t * 4 + 3];
        float mu = s / 768.f;
        float var = s2 / 768.f - mu * mu;
        muS[t] = mu;
        rsS[t] = rsqrtf(var + 1e-5f);
    }
    __syncthreads();

    // ---- LN + GELU -> H1 (aliases XT+W1B0; both dead) ----
    ushort_t* H1u = (ushort_t*)(LB + OFF_H1);
    {
        float muR[2][4], rsR[2][4];
        #pragma unroll
        for (int mt = 0; mt < 2; ++mt)
            #pragma unroll
            for (int reg = 0; reg < 4; ++reg) {
                int row = wm * 32 + mt * 16 + q * 4 + reg;
                muR[mt][reg] = muS[row];
                rsR[mt][reg] = rsS[row];
            }
        #pragma unroll
        for (int nt = 0; nt < 12; ++nt) {
            int c = wn * 192 + nt * 16 + mcol;
            float gv = g1[c], bev = be1[c];
            #pragma unroll
            for (int mt = 0; mt < 2; ++mt)
                #pragma unroll
                for (int reg = 0; reg < 4; ++reg) {
                    int row = wm * 32 + mt * 16 + q * 4 + reg;
                    float v = fmaf((acc1[mt][nt][reg] - muR[mt][reg]) * rsR[mt][reg], gv, bev);
                    H1u[row * SH + c] = f2bf(gelu_f(v));
                }
        }
    }
    __syncthreads();

    // ---- GEMM2: [64x768] @ [768x256], 24 K-steps, double-buffered ----
    f32x4 acc2[2][4];
    #pragma unroll
    for (int mt = 0; mt < 2; ++mt)
        #pragma unroll
        for (int nt = 0; nt < 4; ++nt)
            acc2[mt][nt] = (f32x4){0.f, 0.f, 0.f, 0.f};

    #pragma unroll 1
    for (int s = 0; s < 24; ++s) {
        if (s < 23)
            stage_w2(W2T, LB + ((s & 1) ? OFF_W2B0 : OFF_W2B1), w, lane, (s + 1) * 32);
        const int kk = s * 32;
        const char* wb = LB + ((s & 1) ? OFF_W2B1 : OFF_W2B0);
        bf16x8 a0 = *(const bf16x8*)&H1u[(wm * 32 + mcol) * SH + kk + kq];
        bf16x8 a1 = *(const bf16x8*)&H1u[(wm * 32 + 16 + mcol) * SH + kk + kq];
        #pragma unroll
        for (int nt = 0; nt < 4; ++nt) {
            int nl = wn * 64 + nt * 16 + mcol;
            bf16x8 b = *(const bf16x8*)(wb + nl * 64 + sw);
            acc2[0][nt] = MFMA(a0, b, acc2[0][nt]);
            acc2[1][nt] = MFMA(a1, b, acc2[1][nt]);
        }
        __syncthreads();
    }

    // ---- epilogue: +b2, bf16, bounce via LDS (W2 buffers dead) ----
    ushort_t* Ob = (ushort_t*)(LB + OFF_OB);
    {
        #pragma unroll
        for (int nt = 0; nt < 4; ++nt) {
            int col = wn * 64 + nt * 16 + mcol;
            float bv = b2[col];
            #pragma unroll
            for (int mt = 0; mt < 2; ++mt)
                #pragma unroll
                for (int reg = 0; reg < 4; ++reg) {
                    int row = wm * 32 + mt * 16 + q * 4 + reg;
                    Ob[row * SO + col] = f2bf(acc2[mt][nt][reg] + bv);
                }
        }
    }
    __syncthreads();
    {
        // 64 rows x 8 segs of 64B = 4 x uint4 per thread
        int r = t >> 3, seg = t & 7;
        if (row0 + r < N_NODES) {
            const uint4* src = (const uint4*)&Ob[r * SO + seg * 32];
            uint4* dst = (uint4*)&Hbf[(size_t)(row0 + r) * D_OUT + seg * 32];
            #pragma unroll
            for (int j = 0; j < 4; ++j) dst[j] = src[j];
        }
    }
}

// ---------------------------------------------------------------------------
// K2: fused aggregation + dual-MFMA + residual + LN. 16 rows/block, 4 waves.
// ---------------------------------------------------------------------------
#define SA 264   // (256+8) bf16

__global__ __launch_bounds__(256) void aggfin_mfma(
    const ushort_t* __restrict__ Hbf, const int* __restrict__ rowptr,
    const int* __restrict__ eid,
    const ushort_t* __restrict__ WlT, const float* __restrict__ bl,
    const ushort_t* __restrict__ WrT, const float* __restrict__ g2,
    const float* __restrict__ be2, float* __restrict__ out)
{
    __shared__ __align__(16) ushort_t Ma[16 * SA];
    __shared__ __align__(16) ushort_t Ha[16 * SA];
    __shared__ float redS[16 * 4], redS2[16 * 4], muS[16], rsS[16];

    const int t = threadIdx.x;
    const int w = t >> 6, lane = t & 63;
    const int q = lane >> 4, mcol = lane & 15;
    const int kq = q * 8;
    const int row0 = blockIdx.x * 16;

    // gather: mean over neighbors, per dim t
    #pragma unroll 1
    for (int r = 0; r < 16; ++r) {
        int n = row0 + r;
        int start = rowptr[n], end = rowptr[n + 1];
        float acc = 0.f;
        int e = start;
        for (; e + 4 <= end; e += 4) {
            int s0 = eid[e], s1 = eid[e + 1], s2 = eid[e + 2], s3 = eid[e + 3];
            acc += bf2f(Hbf[(size_t)s0 * D_OUT + t]) + bf2f(Hbf[(size_t)s1 * D_OUT + t])
                 + bf2f(Hbf[(size_t)s2 * D_OUT + t]) + bf2f(Hbf[(size_t)s3 * D_OUT + t]);
        }
        for (; e < end; ++e) acc += bf2f(Hbf[(size_t)eid[e] * D_OUT + t]);
        float inv = (end > start) ? 1.f / (float)(end - start) : 1.f;
        Ma[r * SA + t] = f2bf(acc * inv);
        Ha[r * SA + t] = Hbf[(size_t)n * D_OUT + t];
    }
    __syncthreads();

    // dual MFMA: sage = mean@Wl + h@Wr  (M=16, N=256, K=256)
    f32x4 acc[4];
    #pragma unroll
    for (int nt = 0; nt < 4; ++nt) acc[nt] = (f32x4){0.f, 0.f, 0.f, 0.f};

    for (int kk = 0; kk < D_OUT; kk += 32) {
        bf16x8 am = *(const bf16x8*)&Ma[mcol * SA + kk + kq];
        bf16x8 ah = *(const bf16x8*)&Ha[mcol * SA + kk + kq];
        #pragma unroll
        for (int nt = 0; nt < 4; ++nt) {
            int n = w * 64 + nt * 16 + mcol;
            bf16x8 bL = *(const bf16x8*)&WlT[(size_t)n * D_OUT + kk + kq];
            bf16x8 bR = *(const bf16x8*)&WrT[(size_t)n * D_OUT + kk + kq];
            acc[nt] = MFMA(am, bL, acc[nt]);
            acc[nt] = MFMA(ah, bR, acc[nt]);
        }
    }

    // y = h + sage + bl ; LN over 256 cols
    float y[4][4];
    {
        #pragma unroll
        for (int nt = 0; nt < 4; ++nt) {
            int col = w * 64 + nt * 16 + mcol;
            float bv = bl[col];
            #pragma unroll
            for (int reg = 0; reg < 4; ++reg) {
                int row = q * 4 + reg;
                y[nt][reg] = acc[nt][reg] + bv + bf2f(Ha[row * SA + col]);
            }
        }
    }
    #pragma unroll
    for (int reg = 0; reg < 4; ++reg) {
        float s = 0.f, s2 = 0.f;
        #pragma unroll
        for (int nt = 0; nt < 4; ++nt) { float v = y[nt][reg]; s += v; s2 += v * v; }
        #pragma unroll
        for (int m = 1; m <= 8; m <<= 1) {
            s  += __shfl_xor(s,  m, 64);
            s2 += __shfl_xor(s2, m, 64);
        }
        if (mcol == 0) {
            int row = q * 4 + reg;
            redS[row * 4 + w] = s;
            redS2[row * 4 + w] = s2;
        }
    }
    __syncthreads();
    if (t < 16) {
        float s  = redS[t * 4] + redS[t * 4 + 1] + redS[t * 4 + 2] + redS[t * 4 + 3];
        float s2 = redS2[t * 4] + redS2[t * 4 + 1] + redS2[t * 4 + 2] + redS2[t * 4 + 3];
        float mu = s / 256.f;
        float var = s2 / 256.f - mu * mu;
        muS[t] = mu;
        rsS[t] = rsqrtf(var + 1e-5f);
    }
    __syncthreads();
    {
        #pragma unroll
        for (int nt = 0; nt < 4; ++nt) {
            int col = w * 64 + nt * 16 + mcol;
            float gv = g2[col], bv = be2[col];
            #pragma unroll
            for (int reg = 0; reg < 4; ++reg) {
                int row = q * 4 + reg;
                out[(size_t)(row0 + row) * D_OUT + col] =
                    (y[nt][reg] - muS[row]) * rsS[row] * gv + bv;
            }
        }
    }
}

extern "C" void kernel_launch(void* const* d_in, const int* in_sizes, int n_in,
                              void* d_out, int out_size, void* d_ws, size_t ws_size,
                              hipStream_t stream)
{
    const float* X   = (const float*)d_in[0];
    const int*   edg = (const int*)  d_in[1];
    const float* W1  = (const float*)d_in[2];
    const float* b1  = (const float*)d_in[3];
    const float* g1  = (const float*)d_in[4];
    const float* be1 = (const float*)d_in[5];
    const float* W2  = (const float*)d_in[6];
    const float* b2  = (const float*)d_in[7];
    const float* Wl  = (const float*)d_in[8];
    const float* bl  = (const float*)d_in[9];
    const float* Wr  = (const float*)d_in[10];
    const float* g2  = (const float*)d_in[11];
    const float* be2 = (const float*)d_in[12];

    float* out = (float*)d_out;

    // workspace layout (all 16B aligned)
    char* p = (char*)d_ws;
    ushort_t* Hbf = (ushort_t*)p;  p += (size_t)N_NODES * D_OUT * sizeof(ushort_t); // 51.2MB
    ushort_t* W1T = (ushort_t*)p;  p += (size_t)D_HID * D_IN * sizeof(ushort_t);
    ushort_t* W2T = (ushort_t*)p;  p += (size_t)D_OUT * D_HID * sizeof(ushort_t);
    ushort_t* WlT = (ushort_t*)p;  p += (size_t)D_OUT * D_OUT * sizeof(ushort_t);
    ushort_t* WrT = (ushort_t*)p;  p += (size_t)D_OUT * D_OUT * sizeof(ushort_t);
    int* deg    = (int*)p;         p += (size_t)(N_NODES + 16) * sizeof(int);
    int* rowptr = (int*)p;         p += (size_t)(N_NODES + 16) * sizeof(int);
    int* cursor = (int*)p;         p += (size_t)(N_NODES + 16) * sizeof(int);
    int* bsum   = (int*)p;         p += (size_t)128 * sizeof(int);
    int* boff   = (int*)p;         p += (size_t)128 * sizeof(int);
    int* eid    = (int*)p;

    hipMemsetAsync(deg, 0, (size_t)N_NODES * sizeof(int), stream);

    // weight prep (bf16 transposes)
    transconv_kernel<<<(D_IN * D_HID + 255) / 256, 256, 0, stream>>>(W1, W1T, D_IN, D_HID);
    transconv_kernel<<<(D_HID * D_OUT + 255) / 256, 256, 0, stream>>>(W2, W2T, D_HID, D_OUT);
    transconv_kernel<<<(D_OUT * D_OUT + 255) / 256, 256, 0, stream>>>(Wl, WlT, D_OUT, D_OUT);
    transconv_kernel<<<(D_OUT * D_OUT + 255) / 256, 256, 0, stream>>>(Wr, WrT, D_OUT, D_OUT);

    // CSR build (coalesced 3-phase scan)
    hist_kernel<<<N_EDGES / 256, 256, 0, stream>>>(edg, deg);
    scan1_kernel<<<NBS, 1024, 0, stream>>>(deg, bsum);
    scan2_kernel<<<1, 64, 0, stream>>>(bsum, boff, rowptr);
    scan3_kernel<<<NBS, 1024, 0, stream>>>(deg, boff, rowptr, cursor);
    fill_kernel<<<N_EDGES / 256, 256, 0, stream>>>(edg, cursor, eid);

    // main pipeline
    encoder_mfma<<<(N_NODES + BM - 1) / BM, 512, 0, stream>>>(X, W1T, b1, g1, be1, W2T, b2, Hbf);
    aggfin_mfma<<<N_NODES / 16, 256, 0, stream>>>(Hbf, rowptr, eid, WlT, bl, WrT, g2, be2, out);
}

// Round 3
// 963.168 us; speedup vs baseline: 1.5228x; 1.0704x over previous
//
#include <hip/hip_runtime.h>
#include <hip/hip_bf16.h>
#include <math.h>

#define N_NODES 100000
#define N_EDGES 1600000
#define D_IN    384
#define D_HID   768
#define D_OUT   256

typedef unsigned short ushort_t;
typedef __attribute__((ext_vector_type(8))) short bf16x8;
typedef __attribute__((ext_vector_type(4))) float f32x4;

#define MFMA(a, b, c) __builtin_amdgcn_mfma_f32_16x16x32_bf16((a), (b), (c), 0, 0, 0)

__device__ __forceinline__ ushort_t f2bf(float f) {
    unsigned u = __builtin_bit_cast(unsigned, f);
    u += 0x7fffu + ((u >> 16) & 1u);   // RNE
    return (ushort_t)(u >> 16);
}
__device__ __forceinline__ float bf2f(ushort_t h) {
    return __builtin_bit_cast(float, ((unsigned)h) << 16);
}
__device__ __forceinline__ float gelu_f(float x) {
    // tanh-form GELU as x * sigmoid(2u), 2u = 1.5957691 x + 0.0713549 x^3
    float x2 = x * x;
    float tt = x * fmaf(x2, -0.0713549f, -1.5957691f);
    float e = __expf(tt);                       // exp(-2u)
    return x * __builtin_amdgcn_rcpf(1.f + e);  // x * sigmoid(2u)
}

// 8 consecutive fp32 -> bf16x8 MFMA fragment, 2 loads + 4 cvt_pk (RNE)
__device__ __forceinline__ bf16x8 load_cvt8(const float* __restrict__ p) {
    float4 va = *(const float4*)p;
    float4 vb = *(const float4*)(p + 4);
    union { unsigned u[4]; bf16x8 v; } r;
    asm("v_cvt_pk_bf16_f32 %0, %1, %2" : "=v"(r.u[0]) : "v"(va.x), "v"(va.y));
    asm("v_cvt_pk_bf16_f32 %0, %1, %2" : "=v"(r.u[1]) : "v"(va.z), "v"(va.w));
    asm("v_cvt_pk_bf16_f32 %0, %1, %2" : "=v"(r.u[2]) : "v"(vb.x), "v"(vb.y));
    asm("v_cvt_pk_bf16_f32 %0, %1, %2" : "=v"(r.u[3]) : "v"(vb.z), "v"(vb.w));
    return r.v;
}

// global -> LDS direct, 16B per lane (wave-uniform LDS base + lane*16)
typedef __attribute__((address_space(1))) const unsigned GASU;
typedef __attribute__((address_space(3))) unsigned LASU;
__device__ __forceinline__ void gll16(const void* g, void* l) {
    __builtin_amdgcn_global_load_lds((GASU*)g, (LASU*)l, 16, 0, 0);
}

// ---------------------------------------------------------------------------
// transpose + fp32->bf16: WT[n*K + k] = bf16(W[k*N + n])
// ---------------------------------------------------------------------------
__global__ __launch_bounds__(256) void transconv_kernel(
    const float* __restrict__ W, ushort_t* __restrict__ WT, int K, int N)
{
    int idx = blockIdx.x * 256 + threadIdx.x;
    if (idx >= K * N) return;
    int n = idx / K, k = idx % K;
    WT[idx] = f2bf(W[(size_t)k * N + n]);
}

// same, plus identity on the diagonal (residual fold: WrI = Wr + I)
__global__ __launch_bounds__(256) void transconv_diag_kernel(
    const float* __restrict__ W, ushort_t* __restrict__ WT, int K, int N)
{
    int idx = blockIdx.x * 256 + threadIdx.x;
    if (idx >= K * N) return;
    int n = idx / K, k = idx % K;
    float v = W[(size_t)k * N + n] + ((n == k) ? 1.0f : 0.0f);
    WT[idx] = f2bf(v);
}

// ---------------------------------------------------------------------------
// CSR build
// ---------------------------------------------------------------------------
__global__ __launch_bounds__(256) void hist_kernel(
    const int* __restrict__ edges, int* __restrict__ deg)
{
    int e = blockIdx.x * 256 + threadIdx.x;
    atomicAdd(&deg[edges[N_EDGES + e]], 1);
}

#define NBS 98   // ceil(100000/1024)

__global__ __launch_bounds__(1024) void scan1_kernel(
    const int* __restrict__ deg, int* __restrict__ bsum)
{
    __shared__ int wsum[16];
    int t = threadIdx.x;
    int i = blockIdx.x * 1024 + t;
    int v = (i < N_NODES) ? deg[i] : 0;
    #pragma unroll
    for (int m = 1; m <= 32; m <<= 1) v += __shfl_xor(v, m, 64);
    if ((t & 63) == 0) wsum[t >> 6] = v;
    __syncthreads();
    if (t < 16) {
        int s = wsum[t];
        #pragma unroll
        for (int m = 1; m <= 8; m <<= 1) s += __shfl_xor(s, m, 16);
        if (t == 0) bsum[blockIdx.x] = s;
    }
}

__global__ __launch_bounds__(64) void scan2_kernel(
    const int* __restrict__ bsum, int* __restrict__ boff, int* __restrict__ rowptr)
{
    if (threadIdx.x == 0) {
        int r = 0;
        for (int i = 0; i < NBS; ++i) { boff[i] = r; r += bsum[i]; }
        rowptr[N_NODES] = r;
    }
}

__global__ __launch_bounds__(1024) void scan3_kernel(
    const int* __restrict__ deg, const int* __restrict__ boff,
    int* __restrict__ rowptr, int* __restrict__ cursor)
{
    __shared__ int sc[1024];
    int t = threadIdx.x;
    int i = blockIdx.x * 1024 + t;
    int v = (i < N_NODES) ? deg[i] : 0;
    sc[t] = v;
    __syncthreads();
    for (int off = 1; off < 1024; off <<= 1) {
        int u = (t >= off) ? sc[t - off] : 0;
        __syncthreads();
        sc[t] += u;
        __syncthreads();
    }
    int excl = sc[t] - v;
    if (i < N_NODES) {
        int rp = boff[blockIdx.x] + excl;
        rowptr[i] = rp;
        cursor[i] = rp;
    }
}

__global__ __launch_bounds__(256) void fill_kernel(
    const int* __restrict__ edges, int* __restrict__ cursor,
    int* __restrict__ eid)
{
    int e = blockIdx.x * 256 + threadIdx.x;
    int d = edges[N_EDGES + e];
    int pos = atomicAdd(&cursor[d], 1);
    eid[pos] = edges[e];
}

// ---------------------------------------------------------------------------
// K1: LDS-tiled double-buffered MFMA encoder. BM=64 rows/block, 8 waves.
// (unchanged from round 2 - see comments there)
// ---------------------------------------------------------------------------
#define BM 64
#define SX 392    // XT stride (bf16)
#define SH 776    // H1 stride (bf16)
#define SO 264    // out-bounce stride (bf16)

#define OFF_XT   0
#define OFF_W1B0 50176
#define OFF_W1B1 99328
#define OFF_W2B0 99328
#define OFF_W2B1 115712
#define OFF_OB   99328
#define OFF_H1   0
#define OFF_RED  148480
#define OFF_RED2 149504
#define OFF_MU   150528
#define OFF_RS   150784
#define LDS_TOT  151040

// stage a [768 n x 32 k] bf16 W1 K-slice: 6 x 1KB gll per wave
__device__ __forceinline__ void stage_w1(
    const ushort_t* __restrict__ W1T, char* buf, int w, int lane, int kk)
{
    int qsrc = (lane & 3) ^ ((lane >> 3) & 3);   // slot->k-quarter (involution)
    #pragma unroll
    for (int j = 0; j < 6; ++j) {
        int n = (w * 6 + j) * 16 + (lane >> 2);
        gll16(W1T + (size_t)n * D_IN + kk + qsrc * 8, buf + (w * 6 + j) * 1024);
    }
}

// stage a [256 n x 32 k] bf16 W2 K-slice: 2 x 1KB gll per wave
__device__ __forceinline__ void stage_w2(
    const ushort_t* __restrict__ W2T, char* buf, int w, int lane, int kk)
{
    int qsrc = (lane & 3) ^ ((lane >> 3) & 3);
    #pragma unroll
    for (int j = 0; j < 2; ++j) {
        int n = (w * 2 + j) * 16 + (lane >> 2);
        gll16(W2T + (size_t)n * D_HID + kk + qsrc * 8, buf + (w * 2 + j) * 1024);
    }
}

__global__ __launch_bounds__(512, 2) void encoder_mfma(
    const float* __restrict__ X, const ushort_t* __restrict__ W1T,
    const float* __restrict__ b1, const float* __restrict__ g1,
    const float* __restrict__ be1, const ushort_t* __restrict__ W2T,
    const float* __restrict__ b2, ushort_t* __restrict__ Hbf)
{
    __shared__ __align__(16) char LB[LDS_TOT];

    const int t = threadIdx.x;
    const int w = t >> 6, lane = t & 63;
    const int wm = w >> 2, wn = w & 3;
    const int q = lane >> 4, mcol = lane & 15;
    const int kq = q * 8;
    const int sw = ((q ^ ((mcol >> 1) & 3)) << 4);  // swizzled 16B slot offset
    const int row0 = blockIdx.x * BM;

    ushort_t* XTu = (ushort_t*)(LB + OFF_XT);
    float* redS  = (float*)(LB + OFF_RED);
    float* redS2 = (float*)(LB + OFF_RED2);
    float* muS   = (float*)(LB + OFF_MU);
    float* rsS   = (float*)(LB + OFF_RS);

    // ---- prologue: issue W1 step-0 stage, then stage X tile (fp32->bf16) ----
    stage_w1(W1T, LB + OFF_W1B0, w, lane, 0);
    #pragma unroll
    for (int j = 0; j < 6; ++j) {
        int seg = t + j * 512;             // 3072 segs of 8 floats
        int row = seg / 48, cs = seg % 48;
        int rg = row0 + row; if (rg > N_NODES - 1) rg = N_NODES - 1;
        bf16x8 v = load_cvt8(X + (size_t)rg * D_IN + cs * 8);
        *(bf16x8*)&XTu[row * SX + cs * 8] = v;
    }
    __syncthreads();

    // ---- GEMM1: [64x384] @ [384x768], 12 K-steps, double-buffered ----
    f32x4 acc1[2][12];
    #pragma unroll
    for (int mt = 0; mt < 2; ++mt)
        #pragma unroll
        for (int nt = 0; nt < 12; ++nt)
            acc1[mt][nt] = (f32x4){0.f, 0.f, 0.f, 0.f};

    #pragma unroll 1
    for (int s = 0; s < 12; ++s) {
        if (s < 11)
            stage_w1(W1T, LB + ((s & 1) ? OFF_W1B0 : OFF_W1B1), w, lane, (s + 1) * 32);
        const int kk = s * 32;
        const char* wb = LB + ((s & 1) ? OFF_W1B1 : OFF_W1B0);
        bf16x8 a0 = *(const bf16x8*)&XTu[(wm * 32 + mcol) * SX + kk + kq];
        bf16x8 a1 = *(const bf16x8*)&XTu[(wm * 32 + 16 + mcol) * SX + kk + kq];
        #pragma unroll
        for (int nt = 0; nt < 12; ++nt) {
            int nl = wn * 192 + nt * 16 + mcol;
            bf16x8 b = *(const bf16x8*)(wb + nl * 64 + sw);
            acc1[0][nt] = MFMA(a0, b, acc1[0][nt]);
            acc1[1][nt] = MFMA(a1, b, acc1[1][nt]);
        }
        __syncthreads();
    }

    // prefetch W2 step-0 (into W1B1 region - dead now) under the LN phase
    stage_w2(W2T, LB + OFF_W2B0, w, lane, 0);

    // ---- bias b1 + LN stats ----
    #pragma unroll
    for (int nt = 0; nt < 12; ++nt) {
        float bv = b1[wn * 192 + nt * 16 + mcol];
        #pragma unroll
        for (int mt = 0; mt < 2; ++mt)
            #pragma unroll
            for (int reg = 0; reg < 4; ++reg)
                acc1[mt][nt][reg] += bv;
    }
    #pragma unroll
    for (int mt = 0; mt < 2; ++mt) {
        #pragma unroll
        for (int reg = 0; reg < 4; ++reg) {
            float s = 0.f, s2 = 0.f;
            #pragma unroll
            for (int nt = 0; nt < 12; ++nt) {
                float v = acc1[mt][nt][reg];
                s += v; s2 += v * v;
            }
            #pragma unroll
            for (int m = 1; m <= 8; m <<= 1) {
                s  += __shfl_xor(s,  m, 64);
                s2 += __shfl_xor(s2, m, 64);
            }
            if (mcol == 0) {
                int row = wm * 32 + mt * 16 + q * 4 + reg;
                redS[row * 4 + wn] = s;
                redS2[row * 4 + wn] = s2;
            }
        }
    }
    __syncthreads();
    if (t < BM) {
        float s  = redS[t * 4] + redS[t * 4 + 1] + redS[t * 4 + 2] + redS[t * 4 + 3];
        float s2 = redS2[t * 4] + redS2[t * 4 + 1] + redS2[t * 4 + 2] + redS2[t * 4 + 3];
        float mu = s / 768.f;
        float var = s2 / 768.f - mu * mu;
        muS[t] = mu;
        rsS[t] = rsqrtf(var + 1e-5f);
    }
    __syncthreads();

    // ---- LN + GELU -> H1 (aliases XT+W1B0; both dead) ----
    ushort_t* H1u = (ushort_t*)(LB + OFF_H1);
    {
        float muR[2][4], rsR[2][4];
        #pragma unroll
        for (int mt = 0; mt < 2; ++mt)
            #pragma unroll
            for (int reg = 0; reg < 4; ++reg) {
                int row = wm * 32 + mt * 16 + q * 4 + reg;
                muR[mt][reg] = muS[row];
                rsR[mt][reg] = rsS[row];
            }
        #pragma unroll
        for (int nt = 0; nt < 12; ++nt) {
            int c = wn * 192 + nt * 16 + mcol;
            float gv = g1[c], bev = be1[c];
            #pragma unroll
            for (int mt = 0; mt < 2; ++mt)
                #pragma unroll
                for (int reg = 0; reg < 4; ++reg) {
                    int row = wm * 32 + mt * 16 + q * 4 + reg;
                    float v = fmaf((acc1[mt][nt][reg] - muR[mt][reg]) * rsR[mt][reg], gv, bev);
                    H1u[row * SH + c] = f2bf(gelu_f(v));
                }
        }
    }
    __syncthreads();

    // ---- GEMM2: [64x768] @ [768x256], 24 K-steps, double-buffered ----
    f32x4 acc2[2][4];
    #pragma unroll
    for (int mt = 0; mt < 2; ++mt)
        #pragma unroll
        for (int nt = 0; nt < 4; ++nt)
            acc2[mt][nt] = (f32x4){0.f, 0.f, 0.f, 0.f};

    #pragma unroll 1
    for (int s = 0; s < 24; ++s) {
        if (s < 23)
            stage_w2(W2T, LB + ((s & 1) ? OFF_W2B0 : OFF_W2B1), w, lane, (s + 1) * 32);
        const int kk = s * 32;
        const char* wb = LB + ((s & 1) ? OFF_W2B1 : OFF_W2B0);
        bf16x8 a0 = *(const bf16x8*)&H1u[(wm * 32 + mcol) * SH + kk + kq];
        bf16x8 a1 = *(const bf16x8*)&H1u[(wm * 32 + 16 + mcol) * SH + kk + kq];
        #pragma unroll
        for (int nt = 0; nt < 4; ++nt) {
            int nl = wn * 64 + nt * 16 + mcol;
            bf16x8 b = *(const bf16x8*)(wb + nl * 64 + sw);
            acc2[0][nt] = MFMA(a0, b, acc2[0][nt]);
            acc2[1][nt] = MFMA(a1, b, acc2[1][nt]);
        }
        __syncthreads();
    }

    // ---- epilogue: +b2, bf16, bounce via LDS (W2 buffers dead) ----
    ushort_t* Ob = (ushort_t*)(LB + OFF_OB);
    {
        #pragma unroll
        for (int nt = 0; nt < 4; ++nt) {
            int col = wn * 64 + nt * 16 + mcol;
            float bv = b2[col];
            #pragma unroll
            for (int mt = 0; mt < 2; ++mt)
                #pragma unroll
                for (int reg = 0; reg < 4; ++reg) {
                    int row = wm * 32 + mt * 16 + q * 4 + reg;
                    Ob[row * SO + col] = f2bf(acc2[mt][nt][reg] + bv);
                }
        }
    }
    __syncthreads();
    {
        // 64 rows x 8 segs of 64B = 4 x uint4 per thread
        int r = t >> 3, seg = t & 7;
        if (row0 + r < N_NODES) {
            const uint4* src = (const uint4*)&Ob[r * SO + seg * 32];
            uint4* dst = (uint4*)&Hbf[(size_t)(row0 + r) * D_OUT + seg * 32];
            #pragma unroll
            for (int j = 0; j < 4; ++j) dst[j] = src[j];
        }
    }
}

// ---------------------------------------------------------------------------
// K2: fused aggregation + dual-MFMA + LN. 16 rows/block, 4 waves.
// Gather restructured for MLP: wave-per-row (4 rows/wave serial, independent
// streams), lane owns 4 dims (uint2 = 8B -> one 512B coalesced read per edge
// per wave), edge indices read 64-wide once then v_readlane-broadcast (kills
// the eid->Hbf dependent chain), unroll-4 edges in flight.
// Residual folded into the GEMM via WrI = Wr + I.
// ---------------------------------------------------------------------------
#define SA 264   // (256+8) bf16

__global__ __launch_bounds__(256) void aggfin_mfma(
    const ushort_t* __restrict__ Hbf, const int* __restrict__ rowptr,
    const int* __restrict__ eid,
    const ushort_t* __restrict__ WlT, const float* __restrict__ bl,
    const ushort_t* __restrict__ WrIT, const float* __restrict__ g2,
    const float* __restrict__ be2, float* __restrict__ out)
{
    __shared__ __align__(16) ushort_t Ma[16 * SA];
    __shared__ __align__(16) ushort_t Ha[16 * SA];
    __shared__ float redS[16 * 4], redS2[16 * 4], muS[16], rsS[16];

    const int t = threadIdx.x;
    const int w = t >> 6, lane = t & 63;
    const int q = lane >> 4, mcol = lane & 15;
    const int kq = q * 8;
    const int row0 = blockIdx.x * 16;
    const uint2* H2 = (const uint2*)Hbf;   // row stride 64 uint2

    // ---- gather: wave w owns rows w*4 .. w*4+3 ----
    #pragma unroll 1
    for (int i = 0; i < 4; ++i) {
        const int r = w * 4 + i;
        const int n = row0 + r;
        const int start = rowptr[n], end = rowptr[n + 1];
        float a0 = 0.f, a1 = 0.f, a2 = 0.f, a3 = 0.f;

        #pragma unroll 1
        for (int base = start; base < end; base += 64) {
            int e = base + lane;
            int idx = (e < end) ? eid[e] : 0;   // one coalesced 64-wide load
            int m = end - base; if (m > 64) m = 64;
            int j = 0;
            #pragma unroll 1
            for (; j + 4 <= m; j += 4) {
                int s0 = __builtin_amdgcn_readlane(idx, j + 0);
                int s1 = __builtin_amdgcn_readlane(idx, j + 1);
                int s2 = __builtin_amdgcn_readlane(idx, j + 2);
                int s3 = __builtin_amdgcn_readlane(idx, j + 3);
                uint2 v0 = H2[(size_t)s0 * 64 + lane];
                uint2 v1 = H2[(size_t)s1 * 64 + lane];
                uint2 v2 = H2[(size_t)s2 * 64 + lane];
                uint2 v3 = H2[(size_t)s3 * 64 + lane];
                a0 += bf2f((ushort_t)(v0.x & 0xffffu)) + bf2f((ushort_t)(v1.x & 0xffffu))
                    + bf2f((ushort_t)(v2.x & 0xffffu)) + bf2f((ushort_t)(v3.x & 0xffffu));
                a1 += bf2f((ushort_t)(v0.x >> 16)) + bf2f((ushort_t)(v1.x >> 16))
                    + bf2f((ushort_t)(v2.x >> 16)) + bf2f((ushort_t)(v3.x >> 16));
                a2 += bf2f((ushort_t)(v0.y & 0xffffu)) + bf2f((ushort_t)(v1.y & 0xffffu))
                    + bf2f((ushort_t)(v2.y & 0xffffu)) + bf2f((ushort_t)(v3.y & 0xffffu));
                a3 += bf2f((ushort_t)(v0.y >> 16)) + bf2f((ushort_t)(v1.y >> 16))
                    + bf2f((ushort_t)(v2.y >> 16)) + bf2f((ushort_t)(v3.y >> 16));
            }
            #pragma unroll 1
            for (; j < m; ++j) {
                int s0 = __builtin_amdgcn_readlane(idx, j);
                uint2 v0 = H2[(size_t)s0 * 64 + lane];
                a0 += bf2f((ushort_t)(v0.x & 0xffffu));
                a1 += bf2f((ushort_t)(v0.x >> 16));
                a2 += bf2f((ushort_t)(v0.y & 0xffffu));
                a3 += bf2f((ushort_t)(v0.y >> 16));
            }
        }

        float inv = (end > start) ? 1.f / (float)(end - start) : 1.f;
        a0 *= inv; a1 *= inv; a2 *= inv; a3 *= inv;
        unsigned p0, p1;
        asm("v_cvt_pk_bf16_f32 %0, %1, %2" : "=v"(p0) : "v"(a0), "v"(a1));
        asm("v_cvt_pk_bf16_f32 %0, %1, %2" : "=v"(p1) : "v"(a2), "v"(a3));
        *(uint2*)&Ma[r * SA + lane * 4] = (uint2){p0, p1};
        *(uint2*)&Ha[r * SA + lane * 4] = H2[(size_t)n * 64 + lane];
    }
    __syncthreads();

    // dual MFMA: y = mean@Wl + h@WrI  (M=16, N=256, K=256; residual folded)
    f32x4 acc[4];
    #pragma unroll
    for (int nt = 0; nt < 4; ++nt) acc[nt] = (f32x4){0.f, 0.f, 0.f, 0.f};

    for (int kk = 0; kk < D_OUT; kk += 32) {
        bf16x8 am = *(const bf16x8*)&Ma[mcol * SA + kk + kq];
        bf16x8 ah = *(const bf16x8*)&Ha[mcol * SA + kk + kq];
        #pragma unroll
        for (int nt = 0; nt < 4; ++nt) {
            int n = w * 64 + nt * 16 + mcol;
            bf16x8 bL = *(const bf16x8*)&WlT[(size_t)n * D_OUT + kk + kq];
            bf16x8 bR = *(const bf16x8*)&WrIT[(size_t)n * D_OUT + kk + kq];
            acc[nt] = MFMA(am, bL, acc[nt]);
            acc[nt] = MFMA(ah, bR, acc[nt]);
        }
    }

    // y = acc + bl ; LN over 256 cols
    float y[4][4];
    {
        #pragma unroll
        for (int nt = 0; nt < 4; ++nt) {
            int col = w * 64 + nt * 16 + mcol;
            float bv = bl[col];
            #pragma unroll
            for (int reg = 0; reg < 4; ++reg)
                y[nt][reg] = acc[nt][reg] + bv;
        }
    }
    #pragma unroll
    for (int reg = 0; reg < 4; ++reg) {
        float s = 0.f, s2 = 0.f;
        #pragma unroll
        for (int nt = 0; nt < 4; ++nt) { float v = y[nt][reg]; s += v; s2 += v * v; }
        #pragma unroll
        for (int m = 1; m <= 8; m <<= 1) {
            s  += __shfl_xor(s,  m, 64);
            s2 += __shfl_xor(s2, m, 64);
        }
        if (mcol == 0) {
            int row = q * 4 + reg;
            redS[row * 4 + w] = s;
            redS2[row * 4 + w] = s2;
        }
    }
    __syncthreads();
    if (t < 16) {
        float s  = redS[t * 4] + redS[t * 4 + 1] + redS[t * 4 + 2] + redS[t * 4 + 3];
        float s2 = redS2[t * 4] + redS2[t * 4 + 1] + redS2[t * 4 + 2] + redS2[t * 4 + 3];
        float mu = s / 256.f;
        float var = s2 / 256.f - mu * mu;
        muS[t] = mu;
        rsS[t] = rsqrtf(var + 1e-5f);
    }
    __syncthreads();
    {
        #pragma unroll
        for (int nt = 0; nt < 4; ++nt) {
            int col = w * 64 + nt * 16 + mcol;
            float gv = g2[col], bv = be2[col];
            #pragma unroll
            for (int reg = 0; reg < 4; ++reg) {
                int row = q * 4 + reg;
                out[(size_t)(row0 + row) * D_OUT + col] =
                    (y[nt][reg] - muS[row]) * rsS[row] * gv + bv;
            }
        }
    }
}

extern "C" void kernel_launch(void* const* d_in, const int* in_sizes, int n_in,
                              void* d_out, int out_size, void* d_ws, size_t ws_size,
                              hipStream_t stream)
{
    const float* X   = (const float*)d_in[0];
    const int*   edg = (const int*)  d_in[1];
    const float* W1  = (const float*)d_in[2];
    const float* b1  = (const float*)d_in[3];
    const float* g1  = (const float*)d_in[4];
    const float* be1 = (const float*)d_in[5];
    const float* W2  = (const float*)d_in[6];
    const float* b2  = (const float*)d_in[7];
    const float* Wl  = (const float*)d_in[8];
    const float* bl  = (const float*)d_in[9];
    const float* Wr  = (const float*)d_in[10];
    const float* g2  = (const float*)d_in[11];
    const float* be2 = (const float*)d_in[12];

    float* out = (float*)d_out;

    // workspace layout (all 16B aligned)
    char* p = (char*)d_ws;
    ushort_t* Hbf = (ushort_t*)p;  p += (size_t)N_NODES * D_OUT * sizeof(ushort_t); // 51.2MB
    ushort_t* W1T = (ushort_t*)p;  p += (size_t)D_HID * D_IN * sizeof(ushort_t);
    ushort_t* W2T = (ushort_t*)p;  p += (size_t)D_OUT * D_HID * sizeof(ushort_t);
    ushort_t* WlT = (ushort_t*)p;  p += (size_t)D_OUT * D_OUT * sizeof(ushort_t);
    ushort_t* WrT = (ushort_t*)p;  p += (size_t)D_OUT * D_OUT * sizeof(ushort_t);
    int* deg    = (int*)p;         p += (size_t)(N_NODES + 16) * sizeof(int);
    int* rowptr = (int*)p;         p += (size_t)(N_NODES + 16) * sizeof(int);
    int* cursor = (int*)p;         p += (size_t)(N_NODES + 16) * sizeof(int);
    int* bsum   = (int*)p;         p += (size_t)128 * sizeof(int);
    int* boff   = (int*)p;         p += (size_t)128 * sizeof(int);
    int* eid    = (int*)p;

    hipMemsetAsync(deg, 0, (size_t)N_NODES * sizeof(int), stream);

    // weight prep (bf16 transposes; Wr gets +I residual fold)
    transconv_kernel<<<(D_IN * D_HID + 255) / 256, 256, 0, stream>>>(W1, W1T, D_IN, D_HID);
    transconv_kernel<<<(D_HID * D_OUT + 255) / 256, 256, 0, stream>>>(W2, W2T, D_HID, D_OUT);
    transconv_kernel<<<(D_OUT * D_OUT + 255) / 256, 256, 0, stream>>>(Wl, WlT, D_OUT, D_OUT);
    transconv_diag_kernel<<<(D_OUT * D_OUT + 255) / 256, 256, 0, stream>>>(Wr, WrT, D_OUT, D_OUT);

    // CSR build (coalesced 3-phase scan)
    hist_kernel<<<N_EDGES / 256, 256, 0, stream>>>(edg, deg);
    scan1_kernel<<<NBS, 1024, 0, stream>>>(deg, bsum);
    scan2_kernel<<<1, 64, 0, stream>>>(bsum, boff, rowptr);
    scan3_kernel<<<NBS, 1024, 0, stream>>>(deg, boff, rowptr, cursor);
    fill_kernel<<<N_EDGES / 256, 256, 0, stream>>>(edg, cursor, eid);

    // main pipeline
    encoder_mfma<<<(N_NODES + BM - 1) / BM, 512, 0, stream>>>(X, W1T, b1, g1, be1, W2T, b2, Hbf);
    aggfin_mfma<<<N_NODES / 16, 256, 0, stream>>>(Hbf, rowptr, eid, WlT, bl, WrT, g2, be2, out);
}

// Round 4
// 927.150 us; speedup vs baseline: 1.5819x; 1.0388x over previous
//
#include <hip/hip_runtime.h>
#include <hip/hip_bf16.h>
#include <math.h>

#define N_NODES 100000
#define N_EDGES 1600000
#define D_IN    384
#define D_HID   768
#define D_OUT   256

typedef unsigned short ushort_t;
typedef __attribute__((ext_vector_type(8))) short bf16x8;
typedef __attribute__((ext_vector_type(4))) float f32x4;

#define MFMA(a, b, c) __builtin_amdgcn_mfma_f32_16x16x32_bf16((a), (b), (c), 0, 0, 0)

__device__ __forceinline__ ushort_t f2bf(float f) {
    unsigned u = __builtin_bit_cast(unsigned, f);
    u += 0x7fffu + ((u >> 16) & 1u);   // RNE
    return (ushort_t)(u >> 16);
}
__device__ __forceinline__ float bf2f(ushort_t h) {
    return __builtin_bit_cast(float, ((unsigned)h) << 16);
}
__device__ __forceinline__ float gelu_f(float x) {
    // tanh-form GELU as x * sigmoid(2u), 2u = 1.5957691 x + 0.0713549 x^3
    float x2 = x * x;
    float tt = x * fmaf(x2, -0.0713549f, -1.5957691f);
    float e = __expf(tt);                       // exp(-2u)
    return x * __builtin_amdgcn_rcpf(1.f + e);  // x * sigmoid(2u)
}

// 8 consecutive fp32 -> bf16x8 MFMA fragment, 2 loads + 4 cvt_pk (RNE)
__device__ __forceinline__ bf16x8 load_cvt8(const float* __restrict__ p) {
    float4 va = *(const float4*)p;
    float4 vb = *(const float4*)(p + 4);
    union { unsigned u[4]; bf16x8 v; } r;
    asm("v_cvt_pk_bf16_f32 %0, %1, %2" : "=v"(r.u[0]) : "v"(va.x), "v"(va.y));
    asm("v_cvt_pk_bf16_f32 %0, %1, %2" : "=v"(r.u[1]) : "v"(va.z), "v"(va.w));
    asm("v_cvt_pk_bf16_f32 %0, %1, %2" : "=v"(r.u[2]) : "v"(vb.x), "v"(vb.y));
    asm("v_cvt_pk_bf16_f32 %0, %1, %2" : "=v"(r.u[3]) : "v"(vb.z), "v"(vb.w));
    return r.v;
}

// global -> LDS direct, 16B per lane (wave-uniform LDS base + lane*16)
typedef __attribute__((address_space(1))) const unsigned GASU;
typedef __attribute__((address_space(3))) unsigned LASU;
__device__ __forceinline__ void gll16(const void* g, void* l) {
    __builtin_amdgcn_global_load_lds((GASU*)g, (LASU*)l, 16, 0, 0);
}

// ---------------------------------------------------------------------------
// transpose + fp32->bf16: WT[n*K + k] = bf16(W[k*N + n])  (Wl / WrI for K2)
// ---------------------------------------------------------------------------
__global__ __launch_bounds__(256) void transconv_kernel(
    const float* __restrict__ W, ushort_t* __restrict__ WT, int K, int N)
{
    int idx = blockIdx.x * 256 + threadIdx.x;
    if (idx >= K * N) return;
    int n = idx / K, k = idx % K;
    WT[idx] = f2bf(W[(size_t)k * N + n]);
}

// same, plus identity on the diagonal (residual fold: WrI = Wr + I)
__global__ __launch_bounds__(256) void transconv_diag_kernel(
    const float* __restrict__ W, ushort_t* __restrict__ WT, int K, int N)
{
    int idx = blockIdx.x * 256 + threadIdx.x;
    if (idx >= K * N) return;
    int n = idx / K, k = idx % K;
    float v = W[(size_t)k * N + n] + ((n == k) ? 1.0f : 0.0f);
    WT[idx] = f2bf(v);
}

// ---------------------------------------------------------------------------
// packed weight layouts for the encoder stage path:
//   W1P[s][n][k2], s=K-block (BK=32), n=0..767, k2=0..31  (bf16)
//   -> a wave's 1KB stage chunk (16 n-rows x 64B) is CONTIGUOUS in global.
// ---------------------------------------------------------------------------
__global__ __launch_bounds__(256) void pack_w1_kernel(
    const float* __restrict__ W, ushort_t* __restrict__ WP)
{
    int idx = blockIdx.x * 256 + threadIdx.x;   // 12*768*32 = 294912 exact
    int s = idx / (D_HID * 32);
    int r = idx % (D_HID * 32);
    int n = r >> 5, k2 = r & 31;
    WP[idx] = f2bf(W[(size_t)(s * 32 + k2) * D_HID + n]);
}

__global__ __launch_bounds__(256) void pack_w2_kernel(
    const float* __restrict__ W, ushort_t* __restrict__ WP)
{
    int idx = blockIdx.x * 256 + threadIdx.x;   // 24*256*32 = 196608 exact
    int s = idx / (D_OUT * 32);
    int r = idx % (D_OUT * 32);
    int n = r >> 5, k2 = r & 31;
    WP[idx] = f2bf(W[(size_t)(s * 32 + k2) * D_OUT + n]);
}

// ---------------------------------------------------------------------------
// CSR build
// ---------------------------------------------------------------------------
__global__ __launch_bounds__(256) void hist_kernel(
    const int* __restrict__ edges, int* __restrict__ deg)
{
    int e = blockIdx.x * 256 + threadIdx.x;
    atomicAdd(&deg[edges[N_EDGES + e]], 1);
}

#define NBS 98   // ceil(100000/1024)

__global__ __launch_bounds__(1024) void scan1_kernel(
    const int* __restrict__ deg, int* __restrict__ bsum)
{
    __shared__ int wsum[16];
    int t = threadIdx.x;
    int i = blockIdx.x * 1024 + t;
    int v = (i < N_NODES) ? deg[i] : 0;
    #pragma unroll
    for (int m = 1; m <= 32; m <<= 1) v += __shfl_xor(v, m, 64);
    if ((t & 63) == 0) wsum[t >> 6] = v;
    __syncthreads();
    if (t < 16) {
        int s = wsum[t];
        #pragma unroll
        for (int m = 1; m <= 8; m <<= 1) s += __shfl_xor(s, m, 16);
        if (t == 0) bsum[blockIdx.x] = s;
    }
}

__global__ __launch_bounds__(64) void scan2_kernel(
    const int* __restrict__ bsum, int* __restrict__ boff, int* __restrict__ rowptr)
{
    if (threadIdx.x == 0) {
        int r = 0;
        for (int i = 0; i < NBS; ++i) { boff[i] = r; r += bsum[i]; }
        rowptr[N_NODES] = r;
    }
}

__global__ __launch_bounds__(1024) void scan3_kernel(
    const int* __restrict__ deg, const int* __restrict__ boff,
    int* __restrict__ rowptr, int* __restrict__ cursor)
{
    __shared__ int sc[1024];
    int t = threadIdx.x;
    int i = blockIdx.x * 1024 + t;
    int v = (i < N_NODES) ? deg[i] : 0;
    sc[t] = v;
    __syncthreads();
    for (int off = 1; off < 1024; off <<= 1) {
        int u = (t >= off) ? sc[t - off] : 0;
        __syncthreads();
        sc[t] += u;
        __syncthreads();
    }
    int excl = sc[t] - v;
    if (i < N_NODES) {
        int rp = boff[blockIdx.x] + excl;
        rowptr[i] = rp;
        cursor[i] = rp;
    }
}

__global__ __launch_bounds__(256) void fill_kernel(
    const int* __restrict__ edges, int* __restrict__ cursor,
    int* __restrict__ eid)
{
    int e = blockIdx.x * 256 + threadIdx.x;
    int d = edges[N_EDGES + e];
    int pos = atomicAdd(&cursor[d], 1);
    eid[pos] = edges[e];
}

// ---------------------------------------------------------------------------
// K1: LDS-tiled MFMA encoder. BM=64 rows/block, 8 waves.
// Round-4 changes:
//  * weights staged from PACKED layouts (contiguous 1KB per wave-gll)
//  * per-K-step sync = asm vmcnt(0) + raw s_barrier at loop TOP, stage(s+1)
//    issued after the barrier -> stage overlaps compute of step s (T4-style;
//    the compiler's vmcnt(0)-before-__syncthreads drain is gone).
// LDS layout (151040 B, 1 block/CU):
//   [0      ) XT   64 x 392 bf16 (50176)    | aliased later by H1 (64x776)
//   [50176  ) W1B0 (49152)                  |   H1 = XT+W1B0 = 99328 exact
//   [99328  ) W1B1 (49152) | W2B0(16K)+W2B1(16K) | Obuf 64x264 bf16 (33792)
//   [148480 ) redS/redS2/muS/rsS (2560)
// MFMA 16x16x32 layouts (verified m89/m91/m120):
//   A[m=lane&15][k=(lane>>4)*8+j], B row n=lane&15 same k pattern,
//   C/D col=lane&15, row=(lane>>4)*4+reg
// ---------------------------------------------------------------------------
#define BM 64
#define SX 392    // XT stride (bf16)
#define SH 776    // H1 stride (bf16)
#define SO 264    // out-bounce stride (bf16)

#define OFF_XT   0
#define OFF_W1B0 50176
#define OFF_W1B1 99328
#define OFF_W2B0 99328
#define OFF_W2B1 115712
#define OFF_OB   99328
#define OFF_H1   0
#define OFF_RED  148480
#define OFF_RED2 149504
#define OFF_MU   150528
#define OFF_RS   150784
#define LDS_TOT  151040

// stage a [768n x 32k] W1 K-slice from packed layout: 6 x 1KB contiguous gll
__device__ __forceinline__ void stage_w1p(
    const ushort_t* __restrict__ W1P, char* buf, int w, int lane, int s)
{
    // per-lane element offset inside the 1KB chunk: row(lane>>2)*32 + qsrc*8
    int off = ((lane >> 2) << 5) + ((((lane & 3) ^ ((lane >> 3) & 3))) << 3);
    const ushort_t* base = W1P + (size_t)s * (D_HID * 32);
    #pragma unroll
    for (int j = 0; j < 6; ++j) {
        int c = w * 6 + j;
        gll16(base + c * 512 + off, buf + c * 1024);
    }
}

// stage a [256n x 32k] W2 K-slice from packed layout: 2 x 1KB contiguous gll
__device__ __forceinline__ void stage_w2p(
    const ushort_t* __restrict__ W2P, char* buf, int w, int lane, int s)
{
    int off = ((lane >> 2) << 5) + ((((lane & 3) ^ ((lane >> 3) & 3))) << 3);
    const ushort_t* base = W2P + (size_t)s * (D_OUT * 32);
    #pragma unroll
    for (int j = 0; j < 2; ++j) {
        int c = w * 2 + j;
        gll16(base + c * 512 + off, buf + c * 1024);
    }
}

__global__ __launch_bounds__(512, 2) void encoder_mfma(
    const float* __restrict__ X, const ushort_t* __restrict__ W1P,
    const float* __restrict__ b1, const float* __restrict__ g1,
    const float* __restrict__ be1, const ushort_t* __restrict__ W2P,
    const float* __restrict__ b2, ushort_t* __restrict__ Hbf)
{
    __shared__ __align__(16) char LB[LDS_TOT];

    const int t = threadIdx.x;
    const int w = t >> 6, lane = t & 63;
    const int wm = w >> 2, wn = w & 3;
    const int q = lane >> 4, mcol = lane & 15;
    const int kq = q * 8;
    const int sw = ((q ^ ((mcol >> 1) & 3)) << 4);  // swizzled 16B slot offset
    const int row0 = blockIdx.x * BM;

    ushort_t* XTu = (ushort_t*)(LB + OFF_XT);
    float* redS  = (float*)(LB + OFF_RED);
    float* redS2 = (float*)(LB + OFF_RED2);
    float* muS   = (float*)(LB + OFF_MU);
    float* rsS   = (float*)(LB + OFF_RS);

    // ---- prologue: issue W1 step-0 stage, then stage X tile (fp32->bf16) ----
    stage_w1p(W1P, LB + OFF_W1B0, w, lane, 0);
    #pragma unroll
    for (int j = 0; j < 6; ++j) {
        int seg = t + j * 512;             // 3072 segs of 8 floats
        int row = seg / 48, cs = seg % 48;
        int rg = row0 + row; if (rg > N_NODES - 1) rg = N_NODES - 1;
        bf16x8 v = load_cvt8(X + (size_t)rg * D_IN + cs * 8);
        *(bf16x8*)&XTu[row * SX + cs * 8] = v;
    }
    __syncthreads();   // XT visible; stage(0) already retired (in-order vmcnt)

    // ---- GEMM1: [64x384] @ [384x768], 12 K-steps, pipelined dbuf ----
    f32x4 acc1[2][12];
    #pragma unroll
    for (int mt = 0; mt < 2; ++mt)
        #pragma unroll
        for (int nt = 0; nt < 12; ++nt)
            acc1[mt][nt] = (f32x4){0.f, 0.f, 0.f, 0.f};

    #pragma unroll 1
    for (int s = 0; s < 12; ++s) {
        asm volatile("s_waitcnt vmcnt(0)" ::: "memory");   // own stage(s) landed
        __builtin_amdgcn_s_barrier();                      // all waves' stage(s)
        if (s < 11)
            stage_w1p(W1P, LB + (((s + 1) & 1) ? OFF_W1B1 : OFF_W1B0),
                      w, lane, s + 1);                     // overlaps MFMA below
        const int kk = s * 32;
        const char* wb = LB + ((s & 1) ? OFF_W1B1 : OFF_W1B0);
        bf16x8 a0 = *(const bf16x8*)&XTu[(wm * 32 + mcol) * SX + kk + kq];
        bf16x8 a1 = *(const bf16x8*)&XTu[(wm * 32 + 16 + mcol) * SX + kk + kq];
        #pragma unroll
        for (int nt = 0; nt < 12; ++nt) {
            int nl = wn * 192 + nt * 16 + mcol;
            bf16x8 b = *(const bf16x8*)(wb + nl * 64 + sw);
            acc1[0][nt] = MFMA(a0, b, acc1[0][nt]);
            acc1[1][nt] = MFMA(a1, b, acc1[1][nt]);
        }
    }
    __syncthreads();   // all waves done reading W1 buffers

    // prefetch W2 step-0 (into W1B1 first 16KB - dead now) under the LN phase
    stage_w2p(W2P, LB + OFF_W2B0, w, lane, 0);

    // ---- bias b1 + LN stats ----
    #pragma unroll
    for (int nt = 0; nt < 12; ++nt) {
        float bv = b1[wn * 192 + nt * 16 + mcol];
        #pragma unroll
        for (int mt = 0; mt < 2; ++mt)
            #pragma unroll
            for (int reg = 0; reg < 4; ++reg)
                acc1[mt][nt][reg] += bv;
    }
    #pragma unroll
    for (int mt = 0; mt < 2; ++mt) {
        #pragma unroll
        for (int reg = 0; reg < 4; ++reg) {
            float s = 0.f, s2 = 0.f;
            #pragma unroll
            for (int nt = 0; nt < 12; ++nt) {
                float v = acc1[mt][nt][reg];
                s += v; s2 += v * v;
            }
            #pragma unroll
            for (int m = 1; m <= 8; m <<= 1) {
                s  += __shfl_xor(s,  m, 64);
                s2 += __shfl_xor(s2, m, 64);
            }
            if (mcol == 0) {
                int row = wm * 32 + mt * 16 + q * 4 + reg;
                redS[row * 4 + wn] = s;
                redS2[row * 4 + wn] = s2;
            }
        }
    }
    __syncthreads();
    if (t < BM) {
        float s  = redS[t * 4] + redS[t * 4 + 1] + redS[t * 4 + 2] + redS[t * 4 + 3];
        float s2 = redS2[t * 4] + redS2[t * 4 + 1] + redS2[t * 4 + 2] + redS2[t * 4 + 3];
        float mu = s / 768.f;
        float var = s2 / 768.f - mu * mu;
        muS[t] = mu;
        rsS[t] = rsqrtf(var + 1e-5f);
    }
    __syncthreads();

    // ---- LN + GELU -> H1 (aliases XT+W1B0; both dead) ----
    ushort_t* H1u = (ushort_t*)(LB + OFF_H1);
    {
        float muR[2][4], rsR[2][4];
        #pragma unroll
        for (int mt = 0; mt < 2; ++mt)
            #pragma unroll
            for (int reg = 0; reg < 4; ++reg) {
                int row = wm * 32 + mt * 16 + q * 4 + reg;
                muR[mt][reg] = muS[row];
                rsR[mt][reg] = rsS[row];
            }
        #pragma unroll
        for (int nt = 0; nt < 12; ++nt) {
            int c = wn * 192 + nt * 16 + mcol;
            float gv = g1[c], bev = be1[c];
            #pragma unroll
            for (int mt = 0; mt < 2; ++mt)
                #pragma unroll
                for (int reg = 0; reg < 4; ++reg) {
                    int row = wm * 32 + mt * 16 + q * 4 + reg;
                    float v = fmaf((acc1[mt][nt][reg] - muR[mt][reg]) * rsR[mt][reg], gv, bev);
                    H1u[row * SH + c] = f2bf(gelu_f(v));
                }
        }
    }
    __syncthreads();   // H1 visible to all waves (full drain incl. lgkmcnt)

    // ---- GEMM2: [64x768] @ [768x256], 24 K-steps, pipelined dbuf ----
    f32x4 acc2[2][4];
    #pragma unroll
    for (int mt = 0; mt < 2; ++mt)
        #pragma unroll
        for (int nt = 0; nt < 4; ++nt)
            acc2[mt][nt] = (f32x4){0.f, 0.f, 0.f, 0.f};

    #pragma unroll 1
    for (int s = 0; s < 24; ++s) {
        asm volatile("s_waitcnt vmcnt(0)" ::: "memory");
        __builtin_amdgcn_s_barrier();
        if (s < 23)
            stage_w2p(W2P, LB + (((s + 1) & 1) ? OFF_W2B1 : OFF_W2B0),
                      w, lane, s + 1);
        const int kk = s * 32;
        const char* wb = LB + ((s & 1) ? OFF_W2B1 : OFF_W2B0);
        bf16x8 a0 = *(const bf16x8*)&H1u[(wm * 32 + mcol) * SH + kk + kq];
        bf16x8 a1 = *(const bf16x8*)&H1u[(wm * 32 + 16 + mcol) * SH + kk + kq];
        #pragma unroll
        for (int nt = 0; nt < 4; ++nt) {
            int nl = wn * 64 + nt * 16 + mcol;
            bf16x8 b = *(const bf16x8*)(wb + nl * 64 + sw);
            acc2[0][nt] = MFMA(a0, b, acc2[0][nt]);
            acc2[1][nt] = MFMA(a1, b, acc2[1][nt]);
        }
    }
    __syncthreads();   // all waves done reading W2 buffers; OB aliases them

    // ---- epilogue: +b2, bf16, bounce via LDS for coalesced stores ----
    ushort_t* Ob = (ushort_t*)(LB + OFF_OB);
    {
        #pragma unroll
        for (int nt = 0; nt < 4; ++nt) {
            int col = wn * 64 + nt * 16 + mcol;
            float bv = b2[col];
            #pragma unroll
            for (int mt = 0; mt < 2; ++mt)
                #pragma unroll
                for (int reg = 0; reg < 4; ++reg) {
                    int row = wm * 32 + mt * 16 + q * 4 + reg;
                    Ob[row * SO + col] = f2bf(acc2[mt][nt][reg] + bv);
                }
        }
    }
    __syncthreads();
    {
        // 64 rows x 8 segs of 64B = 4 x uint4 per thread
        int r = t >> 3, seg = t & 7;
        if (row0 + r < N_NODES) {
            const uint4* src = (const uint4*)&Ob[r * SO + seg * 32];
            uint4* dst = (uint4*)&Hbf[(size_t)(row0 + r) * D_OUT + seg * 32];
            #pragma unroll
            for (int j = 0; j < 4; ++j) dst[j] = src[j];
        }
    }
}

// ---------------------------------------------------------------------------
// K2: fused aggregation + dual-MFMA + LN. 16 rows/block, 4 waves.
// Wave-per-row gather (independent streams), lane owns 4 dims (8B/edge),
// edge indices read 64-wide then readlane-broadcast. Residual folded (WrI).
// ---------------------------------------------------------------------------
#define SA 264   // (256+8) bf16

__global__ __launch_bounds__(256) void aggfin_mfma(
    const ushort_t* __restrict__ Hbf, const int* __restrict__ rowptr,
    const int* __restrict__ eid,
    const ushort_t* __restrict__ WlT, const float* __restrict__ bl,
    const ushort_t* __restrict__ WrIT, const float* __restrict__ g2,
    const float* __restrict__ be2, float* __restrict__ out)
{
    __shared__ __align__(16) ushort_t Ma[16 * SA];
    __shared__ __align__(16) ushort_t Ha[16 * SA];
    __shared__ float redS[16 * 4], redS2[16 * 4], muS[16], rsS[16];

    const int t = threadIdx.x;
    const int w = t >> 6, lane = t & 63;
    const int q = lane >> 4, mcol = lane & 15;
    const int kq = q * 8;
    const int row0 = blockIdx.x * 16;
    const uint2* H2 = (const uint2*)Hbf;   // row stride 64 uint2

    // ---- gather: wave w owns rows w*4 .. w*4+3 ----
    #pragma unroll 1
    for (int i = 0; i < 4; ++i) {
        const int r = w * 4 + i;
        const int n = row0 + r;
        const int start = rowptr[n], end = rowptr[n + 1];
        float a0 = 0.f, a1 = 0.f, a2 = 0.f, a3 = 0.f;

        #pragma unroll 1
        for (int base = start; base < end; base += 64) {
            int e = base + lane;
            int idx = (e < end) ? eid[e] : 0;   // one coalesced 64-wide load
            int m = end - base; if (m > 64) m = 64;
            int j = 0;
            #pragma unroll 1
            for (; j + 4 <= m; j += 4) {
                int s0 = __builtin_amdgcn_readlane(idx, j + 0);
                int s1 = __builtin_amdgcn_readlane(idx, j + 1);
                int s2 = __builtin_amdgcn_readlane(idx, j + 2);
                int s3 = __builtin_amdgcn_readlane(idx, j + 3);
                uint2 v0 = H2[(size_t)s0 * 64 + lane];
                uint2 v1 = H2[(size_t)s1 * 64 + lane];
                uint2 v2 = H2[(size_t)s2 * 64 + lane];
                uint2 v3 = H2[(size_t)s3 * 64 + lane];
                a0 += bf2f((ushort_t)(v0.x & 0xffffu)) + bf2f((ushort_t)(v1.x & 0xffffu))
                    + bf2f((ushort_t)(v2.x & 0xffffu)) + bf2f((ushort_t)(v3.x & 0xffffu));
                a1 += bf2f((ushort_t)(v0.x >> 16)) + bf2f((ushort_t)(v1.x >> 16))
                    + bf2f((ushort_t)(v2.x >> 16)) + bf2f((ushort_t)(v3.x >> 16));
                a2 += bf2f((ushort_t)(v0.y & 0xffffu)) + bf2f((ushort_t)(v1.y & 0xffffu))
                    + bf2f((ushort_t)(v2.y & 0xffffu)) + bf2f((ushort_t)(v3.y & 0xffffu));
                a3 += bf2f((ushort_t)(v0.y >> 16)) + bf2f((ushort_t)(v1.y >> 16))
                    + bf2f((ushort_t)(v2.y >> 16)) + bf2f((ushort_t)(v3.y >> 16));
            }
            #pragma unroll 1
            for (; j < m; ++j) {
                int s0 = __builtin_amdgcn_readlane(idx, j);
                uint2 v0 = H2[(size_t)s0 * 64 + lane];
                a0 += bf2f((ushort_t)(v0.x & 0xffffu));
                a1 += bf2f((ushort_t)(v0.x >> 16));
                a2 += bf2f((ushort_t)(v0.y & 0xffffu));
                a3 += bf2f((ushort_t)(v0.y >> 16));
            }
        }

        float inv = (end > start) ? 1.f / (float)(end - start) : 1.f;
        a0 *= inv; a1 *= inv; a2 *= inv; a3 *= inv;
        unsigned p0, p1;
        asm("v_cvt_pk_bf16_f32 %0, %1, %2" : "=v"(p0) : "v"(a0), "v"(a1));
        asm("v_cvt_pk_bf16_f32 %0, %1, %2" : "=v"(p1) : "v"(a2), "v"(a3));
        *(uint2*)&Ma[r * SA + lane * 4] = (uint2){p0, p1};
        *(uint2*)&Ha[r * SA + lane * 4] = H2[(size_t)n * 64 + lane];
    }
    __syncthreads();

    // dual MFMA: y = mean@Wl + h@WrI  (M=16, N=256, K=256; residual folded)
    f32x4 acc[4];
    #pragma unroll
    for (int nt = 0; nt < 4; ++nt) acc[nt] = (f32x4){0.f, 0.f, 0.f, 0.f};

    for (int kk = 0; kk < D_OUT; kk += 32) {
        bf16x8 am = *(const bf16x8*)&Ma[mcol * SA + kk + kq];
        bf16x8 ah = *(const bf16x8*)&Ha[mcol * SA + kk + kq];
        #pragma unroll
        for (int nt = 0; nt < 4; ++nt) {
            int n = w * 64 + nt * 16 + mcol;
            bf16x8 bL = *(const bf16x8*)&WlT[(size_t)n * D_OUT + kk + kq];
            bf16x8 bR = *(const bf16x8*)&WrIT[(size_t)n * D_OUT + kk + kq];
            acc[nt] = MFMA(am, bL, acc[nt]);
            acc[nt] = MFMA(ah, bR, acc[nt]);
        }
    }

    // y = acc + bl ; LN over 256 cols
    float y[4][4];
    {
        #pragma unroll
        for (int nt = 0; nt < 4; ++nt) {
            int col = w * 64 + nt * 16 + mcol;
            float bv = bl[col];
            #pragma unroll
            for (int reg = 0; reg < 4; ++reg)
                y[nt][reg] = acc[nt][reg] + bv;
        }
    }
    #pragma unroll
    for (int reg = 0; reg < 4; ++reg) {
        float s = 0.f, s2 = 0.f;
        #pragma unroll
        for (int nt = 0; nt < 4; ++nt) { float v = y[nt][reg]; s += v; s2 += v * v; }
        #pragma unroll
        for (int m = 1; m <= 8; m <<= 1) {
            s  += __shfl_xor(s,  m, 64);
            s2 += __shfl_xor(s2, m, 64);
        }
        if (mcol == 0) {
            int row = q * 4 + reg;
            redS[row * 4 + w] = s;
            redS2[row * 4 + w] = s2;
        }
    }
    __syncthreads();
    if (t < 16) {
        float s  = redS[t * 4] + redS[t * 4 + 1] + redS[t * 4 + 2] + redS[t * 4 + 3];
        float s2 = redS2[t * 4] + redS2[t * 4 + 1] + redS2[t * 4 + 2] + redS2[t * 4 + 3];
        float mu = s / 256.f;
        float var = s2 / 256.f - mu * mu;
        muS[t] = mu;
        rsS[t] = rsqrtf(var + 1e-5f);
    }
    __syncthreads();
    {
        #pragma unroll
        for (int nt = 0; nt < 4; ++nt) {
            int col = w * 64 + nt * 16 + mcol;
            float gv = g2[col], bv = be2[col];
            #pragma unroll
            for (int reg = 0; reg < 4; ++reg) {
                int row = q * 4 + reg;
                out[(size_t)(row0 + row) * D_OUT + col] =
                    (y[nt][reg] - muS[row]) * rsS[row] * gv + bv;
            }
        }
    }
}

extern "C" void kernel_launch(void* const* d_in, const int* in_sizes, int n_in,
                              void* d_out, int out_size, void* d_ws, size_t ws_size,
                              hipStream_t stream)
{
    const float* X   = (const float*)d_in[0];
    const int*   edg = (const int*)  d_in[1];
    const float* W1  = (const float*)d_in[2];
    const float* b1  = (const float*)d_in[3];
    const float* g1  = (const float*)d_in[4];
    const float* be1 = (const float*)d_in[5];
    const float* W2  = (const float*)d_in[6];
    const float* b2  = (const float*)d_in[7];
    const float* Wl  = (const float*)d_in[8];
    const float* bl  = (const float*)d_in[9];
    const float* Wr  = (const float*)d_in[10];
    const float* g2  = (const float*)d_in[11];
    const float* be2 = (const float*)d_in[12];

    float* out = (float*)d_out;

    // workspace layout (all 64B aligned)
    char* p = (char*)d_ws;
    ushort_t* Hbf = (ushort_t*)p;  p += (size_t)N_NODES * D_OUT * sizeof(ushort_t); // 51.2MB
    ushort_t* W1P = (ushort_t*)p;  p += (size_t)D_HID * D_IN * sizeof(ushort_t);
    ushort_t* W2P = (ushort_t*)p;  p += (size_t)D_OUT * D_HID * sizeof(ushort_t);
    ushort_t* WlT = (ushort_t*)p;  p += (size_t)D_OUT * D_OUT * sizeof(ushort_t);
    ushort_t* WrT = (ushort_t*)p;  p += (size_t)D_OUT * D_OUT * sizeof(ushort_t);
    int* deg    = (int*)p;         p += (size_t)(N_NODES + 16) * sizeof(int);
    int* rowptr = (int*)p;         p += (size_t)(N_NODES + 16) * sizeof(int);
    int* cursor = (int*)p;         p += (size_t)(N_NODES + 16) * sizeof(int);
    int* bsum   = (int*)p;         p += (size_t)128 * sizeof(int);
    int* boff   = (int*)p;         p += (size_t)128 * sizeof(int);
    int* eid    = (int*)p;

    hipMemsetAsync(deg, 0, (size_t)N_NODES * sizeof(int), stream);

    // weight prep (packed encoder weights; row-major transposes for K2)
    pack_w1_kernel<<<(D_IN * D_HID) / 256, 256, 0, stream>>>(W1, W1P);
    pack_w2_kernel<<<(D_HID * D_OUT) / 256, 256, 0, stream>>>(W2, W2P);
    transconv_kernel<<<(D_OUT * D_OUT + 255) / 256, 256, 0, stream>>>(Wl, WlT, D_OUT, D_OUT);
    transconv_diag_kernel<<<(D_OUT * D_OUT + 255) / 256, 256, 0, stream>>>(Wr, WrT, D_OUT, D_OUT);

    // CSR build (coalesced 3-phase scan)
    hist_kernel<<<N_EDGES / 256, 256, 0, stream>>>(edg, deg);
    scan1_kernel<<<NBS, 1024, 0, stream>>>(deg, bsum);
    scan2_kernel<<<1, 64, 0, stream>>>(bsum, boff, rowptr);
    scan3_kernel<<<NBS, 1024, 0, stream>>>(deg, boff, rowptr, cursor);
    fill_kernel<<<N_EDGES / 256, 256, 0, stream>>>(edg, cursor, eid);

    // main pipeline
    encoder_mfma<<<(N_NODES + BM - 1) / BM, 512, 0, stream>>>(X, W1P, b1, g1, be1, W2P, b2, Hbf);
    aggfin_mfma<<<N_NODES / 16, 256, 0, stream>>>(Hbf, rowptr, eid, WlT, bl, WrT, g2, be2, out);
}